// Round 1
// baseline (5164.706 us; speedup 1.0000x reference)
//
#include <hip/hip_runtime.h>
#include <math.h>

#define HWSZ 65536
#define NPIX 131072

__device__ __forceinline__ float sigmf(float x){ return 1.f/(1.f+__expf(-x)); }
__device__ __forceinline__ float tanhf2(float x){
  x = fminf(fmaxf(x,-15.f),15.f);
  float e = __expf(2.f*x);
  return (e-1.f)/(e+1.f);
}

// ---------------- weight prep ----------------
__global__ void prep_gru_w(const float* __restrict__ wih, const float* __restrict__ whh,
                           float* __restrict__ Wt){
  int idx = blockIdx.x*256+threadIdx.x;
  if(idx >= 192*384) return;
  int k = idx/384, g = idx - k*384;
  Wt[idx] = (k<64) ? wih[g*64+k] : whh[g*128 + (k-64)];
}

__global__ void prep_conv_w(const float* __restrict__ src, float* __restrict__ dst,
                            int IC, int OC, int KS, int total){
  int idx = blockIdx.x*256+threadIdx.x;
  if(idx>=total) return;
  // dst layout: [ky][ic][kx][oc]
  int oc = idx % OC; int r = idx/OC;
  int kx = r % KS; r /= KS;
  int ic = r % IC; int ky = r/IC;
  dst[idx] = src[((oc*IC+ic)*KS+ky)*KS+kx];
}

// ---------------- mask reductions ----------------
__global__ void flags_kernel(const int* __restrict__ masks, int* __restrict__ flags){
  __shared__ int red[256];
  int b = blockIdx.x; int acc=0;
  const int* m = masks + b*HWSZ;
  for(int i=threadIdx.x;i<HWSZ;i+=256) acc |= (m[i]>0)?1:0;
  red[threadIdx.x]=acc; __syncthreads();
  for(int s=128;s>0;s>>=1){ if(threadIdx.x<s) red[threadIdx.x]|=red[threadIdx.x+s]; __syncthreads(); }
  if(threadIdx.x==0) flags[b]=red[0];
}

__global__ void obs_kernel(const int* __restrict__ masks, const int* __restrict__ flags,
                           float* __restrict__ out){
  int p = blockIdx.x*256+threadIdx.x;
  if(p>=NPIX) return;
  int n = p>>16, hw = p&65535;
  int s=0;
  #pragma unroll
  for(int t=0;t<4;t++) s += masks[((n*4+t)<<16)+hw]*flags[n*4+t];
  out[p]=(float)s;
}

// ---------------- GRU ----------------
// block: 256 threads, 32 pixels through all 4 timesteps.
// axs rows 0..63 = x_t (k-major), rows 64..191 = h (k-major).
// thread (pxg=tid&7, jg=tid>>3): 4 px x gate-cols {j0..j0+3, 128+j0.., 256+j0..}
__launch_bounds__(256)
__global__ void gru_kernel(const float* __restrict__ feat, const int* __restrict__ masks,
                           const float* __restrict__ Wt, const float* __restrict__ bih,
                           const float* __restrict__ bhh, float* __restrict__ S){
  __shared__ __align__(16) float axs[192][32];   // 24576 B
  __shared__ __align__(16) float wsm[16*384];    // 24576 B
  const int tid = threadIdx.x;
  const int p0 = blockIdx.x*32;
  const int n = p0>>16, hw0 = p0&65535;
  const int pxg = tid&7, jg = tid>>3;
  const int px0 = pxg*4, j0 = jg*4;

  // zero h
  for(int i=tid;i<128*32;i+=256) (&axs[64][0])[i]=0.f;

  for(int t=0;t<4;t++){
    __syncthreads();   // prev K-loop / gating done before x restage
    // stage x_t (coalesced float4 over channels, transposed store)
    for(int i=tid;i<32*16;i+=256){
      int c4 = i&15, px = i>>4;
      float4 v = *(const float4*)&feat[ (size_t)(((n*4+t)<<16)|(hw0+px))*64 + c4*4 ];
      axs[c4*4+0][px]=v.x; axs[c4*4+1][px]=v.y; axs[c4*4+2][px]=v.z; axs[c4*4+3][px]=v.w;
    }

    float air[4][4], aiz[4][4], ain[4][4], ahr[4][4], ahz[4][4], ahn[4][4];
    #pragma unroll
    for(int p=0;p<4;p++)
      #pragma unroll
      for(int c=0;c<4;c++){ air[p][c]=0.f;aiz[p][c]=0.f;ain[p][c]=0.f;
                            ahr[p][c]=0.f;ahz[p][c]=0.f;ahn[p][c]=0.f; }

    // x part: chunks 0..3 (k=0..63)
    #pragma unroll 1
    for(int ch=0;ch<4;ch++){
      __syncthreads();
      { const float4* src = (const float4*)(Wt + ch*16*384);
        float4* dst = (float4*)wsm;
        #pragma unroll
        for(int i=0;i<6;i++) dst[tid+i*256]=src[tid+i*256]; }
      __syncthreads();
      #pragma unroll
      for(int kk=0;kk<16;kk++){
        const float4 a = *(const float4*)&axs[ch*16+kk][px0];
        const float4* wrow = (const float4*)&wsm[kk*384];
        const float4 wr = wrow[jg], wz = wrow[32+jg], wn = wrow[64+jg];
        const float av[4]={a.x,a.y,a.z,a.w};
        #pragma unroll
        for(int p=0;p<4;p++){
          air[p][0]+=av[p]*wr.x; air[p][1]+=av[p]*wr.y; air[p][2]+=av[p]*wr.z; air[p][3]+=av[p]*wr.w;
          aiz[p][0]+=av[p]*wz.x; aiz[p][1]+=av[p]*wz.y; aiz[p][2]+=av[p]*wz.z; aiz[p][3]+=av[p]*wz.w;
          ain[p][0]+=av[p]*wn.x; ain[p][1]+=av[p]*wn.y; ain[p][2]+=av[p]*wn.z; ain[p][3]+=av[p]*wn.w;
        }
      }
    }
    // h part: chunks 4..11 (k=64..191)
    #pragma unroll 1
    for(int ch=4;ch<12;ch++){
      __syncthreads();
      { const float4* src = (const float4*)(Wt + ch*16*384);
        float4* dst = (float4*)wsm;
        #pragma unroll
        for(int i=0;i<6;i++) dst[tid+i*256]=src[tid+i*256]; }
      __syncthreads();
      #pragma unroll
      for(int kk=0;kk<16;kk++){
        const float4 a = *(const float4*)&axs[ch*16+kk][px0];
        const float4* wrow = (const float4*)&wsm[kk*384];
        const float4 wr = wrow[jg], wz = wrow[32+jg], wn = wrow[64+jg];
        const float av[4]={a.x,a.y,a.z,a.w};
        #pragma unroll
        for(int p=0;p<4;p++){
          ahr[p][0]+=av[p]*wr.x; ahr[p][1]+=av[p]*wr.y; ahr[p][2]+=av[p]*wr.z; ahr[p][3]+=av[p]*wr.w;
          ahz[p][0]+=av[p]*wz.x; ahz[p][1]+=av[p]*wz.y; ahz[p][2]+=av[p]*wz.z; ahz[p][3]+=av[p]*wz.w;
          ahn[p][0]+=av[p]*wn.x; ahn[p][1]+=av[p]*wn.y; ahn[p][2]+=av[p]*wn.z; ahn[p][3]+=av[p]*wn.w;
        }
      }
    }
    __syncthreads();  // everyone done reading old h before owners overwrite

    // gating: fully thread-local (each (row,px) element owned by exactly one thread)
    int ml[4];
    #pragma unroll
    for(int p=0;p<4;p++) ml[p]=masks[((n*4+t)<<16)+hw0+px0+p];
    #pragma unroll
    for(int c=0;c<4;c++){
      int j=j0+c;
      float br  = bih[j]     + bhh[j];
      float bz  = bih[128+j] + bhh[128+j];
      float bin = bih[256+j];
      float bhn = bhh[256+j];
      float4 h4 = *(const float4*)&axs[64+j][px0];
      float hold[4]={h4.x,h4.y,h4.z,h4.w};
      float hnew[4];
      #pragma unroll
      for(int p=0;p<4;p++){
        float r  = sigmf(air[p][c]+ahr[p][c]+br);
        float z  = sigmf(aiz[p][c]+ahz[p][c]+bz);
        float nn = tanhf2(ain[p][c]+bin + r*(ahn[p][c]+bhn));
        float h2 = (1.f-z)*nn + z*hold[p];
        hnew[p] = (ml[p]>0)? h2 : hold[p];
      }
      float4 hv={hnew[0],hnew[1],hnew[2],hnew[3]};
      *(float4*)&axs[64+j][px0]=hv;
    }
  }
  __syncthreads();
  // write state NHWC (c contiguous)
  for(int i=tid;i<32*32;i+=256){
    int c4=i&31, px=i>>5;
    float4 v={axs[64+c4*4+0][px],axs[64+c4*4+1][px],axs[64+c4*4+2][px],axs[64+c4*4+3][px]};
    *(float4*)&S[(size_t)(p0+px)*128 + c4*4]=v;
  }
}

// ---------------- direct conv (NHWC), raw out + BN partials ----------------
template<int IC,int OC,int KS>
__launch_bounds__(256)
__global__ void conv_kernel(const float* __restrict__ in, const float* __restrict__ Wt,
                            float* __restrict__ out, float* __restrict__ partials){
  constexpr int P=KS/2, WD=64+KS-1, OCT=OC/16;
  __shared__ __align__(16) float ins[16][WD];
  __shared__ __align__(16) float wsm[16*KS*OC];
  const int tid=threadIdx.x;
  const int p0=blockIdx.x*64;
  const int n=p0>>16; const int hw0=p0&65535; const int y0=hw0>>8, x0=hw0&255;
  const int ocg=tid&15, pxg=tid>>4;
  const int oc0=ocg*OCT;
  float acc[4][OCT];
  #pragma unroll
  for(int p=0;p<4;p++)
    #pragma unroll
    for(int o=0;o<OCT;o++) acc[p][o]=0.f;

  for(int ky=0;ky<KS;ky++){
    int ys=y0+ky-P;
    if(ys<0||ys>255) continue;              // uniform across block
    for(int ic0=0;ic0<IC;ic0+=16){
      __syncthreads();
      for(int i=tid;i<16*WD;i+=256){
        int icc=i&15, xx=i>>4;
        int xg=x0-P+xx;
        ins[icc][xx] = (xg>=0&&xg<256)? in[(size_t)(((n<<16)|(ys<<8))+xg)*IC+ic0+icc] : 0.f;
      }
      { const float4* src=(const float4*)(Wt+(size_t)(ky*IC+ic0)*KS*OC);
        float4* dst=(float4*)wsm;
        for(int i=tid;i<16*KS*OC/4;i+=256) dst[i]=src[i]; }
      __syncthreads();
      #pragma unroll
      for(int icc=0;icc<16;icc++){
        #pragma unroll
        for(int kx=0;kx<KS;kx++){
          float a[4];
          #pragma unroll
          for(int p=0;p<4;p++) a[p]=ins[icc][pxg*4+p+kx];
          const float* wrow=&wsm[(icc*KS+kx)*OC+oc0];
          #pragma unroll
          for(int o=0;o<OCT;o++){
            float w=wrow[o];
            #pragma unroll
            for(int p=0;p<4;p++) acc[p][o]+=a[p]*w;
          }
        }
      }
    }
  }
  // raw output
  #pragma unroll
  for(int p=0;p<4;p++){
    int px=pxg*4+p;
    float* orow=&out[(size_t)(p0+px)*OC+oc0];
    #pragma unroll
    for(int o=0;o<OCT;o++) orow[o]=acc[p][o];
  }
  // per-channel partial sums (reuse wsm)
  __syncthreads();
  float* ps1=wsm; float* ps2=wsm+16*OC;
  #pragma unroll
  for(int o=0;o<OCT;o++){
    float s1=0.f,s2=0.f;
    #pragma unroll
    for(int p=0;p<4;p++){ s1+=acc[p][o]; s2+=acc[p][o]*acc[p][o]; }
    ps1[pxg*OC+oc0+o]=s1; ps2[pxg*OC+oc0+o]=s2;
  }
  __syncthreads();
  for(int oc=tid;oc<OC;oc+=256){
    float t1=0.f,t2=0.f;
    #pragma unroll
    for(int g=0;g<16;g++){ t1+=ps1[g*OC+oc]; t2+=ps2[g*OC+oc]; }
    partials[(size_t)blockIdx.x*2*OC+oc]=t1;
    partials[(size_t)blockIdx.x*2*OC+OC+oc]=t2;
  }
}

// ---------------- BN stats finalize ----------------
__global__ void stats_kernel(const float* __restrict__ partials, const float* __restrict__ g,
                             const float* __restrict__ b, float2* __restrict__ stats, int OC){
  __shared__ float r1[256], r2[256];
  int oc=blockIdx.x; int tid=threadIdx.x;
  float s1=0.f,s2=0.f;
  for(int bl=tid;bl<2048;bl+=256){ s1+=partials[bl*2*OC+oc]; s2+=partials[bl*2*OC+OC+oc]; }
  r1[tid]=s1;r2[tid]=s2; __syncthreads();
  for(int s=128;s>0;s>>=1){ if(tid<s){r1[tid]+=r1[tid+s]; r2[tid]+=r2[tid+s];} __syncthreads(); }
  if(tid==0){
    float mean=r1[0]*(1.f/131072.f);
    float var =r2[0]*(1.f/131072.f)-mean*mean;
    float sc=g[oc]*rsqrtf(var+1e-5f);
    float2 st; st.x=sc; st.y=b[oc]-mean*sc;
    stats[oc]=st;
  }
}

__global__ void bnrelu_kernel(float* __restrict__ buf, const float2* __restrict__ stats,
                              int OC4, int total4){
  for(int i=blockIdx.x*256+threadIdx.x;i<total4;i+=gridDim.x*256){
    int c4=i%OC4;
    float4 v=((float4*)buf)[i];
    float2 s0=stats[c4*4+0],s1=stats[c4*4+1],s2=stats[c4*4+2],s3=stats[c4*4+3];
    v.x=fmaxf(0.f,v.x*s0.x+s0.y);
    v.y=fmaxf(0.f,v.y*s1.x+s1.y);
    v.z=fmaxf(0.f,v.z*s2.x+s2.y);
    v.w=fmaxf(0.f,v.w*s3.x+s3.y);
    ((float4*)buf)[i]=v;
  }
}

// ---------------- final 1x1 conv 48->20, NCHW out + bias ----------------
__global__ void obj2_kernel(const float* __restrict__ in, const float* __restrict__ w,
                            const float* __restrict__ bias, float* __restrict__ out){
  __shared__ float wsm[20*48];
  __shared__ float bs[20];
  int tid=threadIdx.x;
  for(int i=tid;i<20*48;i+=256) wsm[i]=w[i];
  if(tid<20) bs[tid]=bias[tid];
  __syncthreads();
  int p=blockIdx.x*256+tid;
  int n=p>>16, hw=p&65535;
  float x[48];
  #pragma unroll
  for(int i=0;i<12;i++) *(float4*)&x[i*4]=*(const float4*)&in[(size_t)p*48+i*4];
  #pragma unroll
  for(int o=0;o<20;o++){
    float s=bs[o];
    #pragma unroll
    for(int c=0;c<48;c++) s+=x[c]*wsm[o*48+c];
    out[(size_t)((n*20+o)<<16)+hw]=s;
  }
}

extern "C" void kernel_launch(void* const* d_in, const int* in_sizes, int n_in,
                              void* d_out, int out_size, void* d_ws, size_t ws_size,
                              hipStream_t stream) {
  const float* feat = (const float*)d_in[0];
  const int*   masks= (const int*)  d_in[1];
  const float* w_ih = (const float*)d_in[2];
  const float* w_hh = (const float*)d_in[3];
  const float* b_ih = (const float*)d_in[4];
  const float* b_hh = (const float*)d_in[5];
  const float* c1w  = (const float*)d_in[6];
  const float* bn1g = (const float*)d_in[7];  const float* bn1b=(const float*)d_in[8];
  const float* c2w  = (const float*)d_in[9];
  const float* bn2g = (const float*)d_in[10]; const float* bn2b=(const float*)d_in[11];
  const float* c3w  = (const float*)d_in[12];
  const float* bn3g = (const float*)d_in[13]; const float* bn3b=(const float*)d_in[14];
  const float* o1w  = (const float*)d_in[15];
  const float* bn4g = (const float*)d_in[16]; const float* bn4b=(const float*)d_in[17];
  const float* o2w  = (const float*)d_in[18]; const float* o2b =(const float*)d_in[19];

  char* ws = (char*)d_ws;
  float* S        = (float*)(ws + 0);            // 67108864 B  [NPIX][128] NHWC
  float* A1       = (float*)(ws + 67108864);     // 67108864 B  [NPIX][128]
  float* A2       = (float*)(ws + 134217728);    // 33554432 B  [NPIX][64]
  float* A3       = S;                           // alias: [NPIX][48] (S dead after conv1)
  float* A4       = A1;                          // alias: [NPIX][48] (A1 dead after conv2)
  float* WtG      = (float*)(ws + 167772160);    // 294912 B
  float* W1t      = (float*)(ws + 168067072);    // 3211264 B
  float* W2t      = (float*)(ws + 171278336);    // 294912 B
  float* W3t      = (float*)(ws + 171573248);    // 110592 B
  float* W4t      = (float*)(ws + 171683840);    // 82944 B
  float* partials = (float*)(ws + 171766784);    // 2097152 B (max 2048*2*128)
  float2* stats   = (float2*)(ws + 173863936);   // 1024 B
  int*   flags    = (int*)  (ws + 173864960);    // 32 B

  float* semmap = (float*)d_out;                 // [2][20][256][256]
  float* obsout = (float*)d_out + 2621440;       // [2][256][256] as float

  prep_gru_w<<<288,256,0,stream>>>(w_ih,w_hh,WtG);
  prep_conv_w<<<(128*128*49+255)/256,256,0,stream>>>(c1w,W1t,128,128,7,128*128*49);
  prep_conv_w<<<(128*64*9 +255)/256,256,0,stream>>>(c2w,W2t,128,64,3,128*64*9);
  prep_conv_w<<<(64*48*9  +255)/256,256,0,stream>>>(c3w,W3t,64,48,3,64*48*9);
  prep_conv_w<<<(48*48*9  +255)/256,256,0,stream>>>(o1w,W4t,48,48,3,48*48*9);

  flags_kernel<<<8,256,0,stream>>>(masks,flags);
  obs_kernel<<<512,256,0,stream>>>(masks,flags,obsout);

  gru_kernel<<<4096,256,0,stream>>>(feat,masks,WtG,b_ih,b_hh,S);

  conv_kernel<128,128,7><<<2048,256,0,stream>>>(S,W1t,A1,partials);
  stats_kernel<<<128,256,0,stream>>>(partials,bn1g,bn1b,stats,128);
  bnrelu_kernel<<<4096,256,0,stream>>>(A1,stats,32,NPIX*128/4);

  conv_kernel<128,64,3><<<2048,256,0,stream>>>(A1,W2t,A2,partials);
  stats_kernel<<<64,256,0,stream>>>(partials,bn2g,bn2b,stats,64);
  bnrelu_kernel<<<4096,256,0,stream>>>(A2,stats,16,NPIX*64/4);

  conv_kernel<64,48,3><<<2048,256,0,stream>>>(A2,W3t,A3,partials);
  stats_kernel<<<48,256,0,stream>>>(partials,bn3g,bn3b,stats,48);
  bnrelu_kernel<<<4096,256,0,stream>>>(A3,stats,12,NPIX*48/4);

  conv_kernel<48,48,3><<<2048,256,0,stream>>>(A3,W4t,A4,partials);
  stats_kernel<<<48,256,0,stream>>>(partials,bn4g,bn4b,stats,48);
  bnrelu_kernel<<<4096,256,0,stream>>>(A4,stats,12,NPIX*48/4);

  obj2_kernel<<<512,256,0,stream>>>(A4,o2w,o2b,semmap);
}

// Round 2
// 2635.263 us; speedup vs baseline: 1.9598x; 1.9598x over previous
//
#include <hip/hip_runtime.h>
#include <hip/hip_bf16.h>
#include <math.h>

#define HWSZ 65536
#define NPIX 131072

typedef __attribute__((ext_vector_type(8))) short short8;
typedef __attribute__((ext_vector_type(4))) float f32x4;

__device__ __forceinline__ float sigmf(float x){ return 1.f/(1.f+__expf(-x)); }
__device__ __forceinline__ float tanhf2(float x){
  x = fminf(fmaxf(x,-15.f),15.f);
  float e = __expf(2.f*x);
  return (e-1.f)/(e+1.f);
}
__device__ __forceinline__ unsigned short f2b(float f){
  __hip_bfloat16 b = __float2bfloat16(f);
  return *(unsigned short*)&b;
}

// ---------------- weight prep ----------------
__global__ void prep_gru_w(const float* __restrict__ wih, const float* __restrict__ whh,
                           float* __restrict__ Wt){
  int idx = blockIdx.x*256+threadIdx.x;
  if(idx >= 192*384) return;
  int k = idx/384, g = idx - k*384;
  Wt[idx] = (k<64) ? wih[g*64+k] : whh[g*128 + (k-64)];
}

// dst layout: [tap(ky*KS+kx)][chunk(ICP/32)][oc][32] bf16, zero-padded ic>=IC
__global__ void prep_conv_w(const float* __restrict__ src, unsigned short* __restrict__ dst,
                            int IC, int ICC, int OC, int KS, int total){
  int idx = blockIdx.x*256+threadIdx.x;
  if(idx>=total) return;
  int icq = idx&31; int r = idx>>5;
  int oc = r%OC; r/=OC;
  int ch = r%ICC; int tap = r/ICC;
  int ky = tap/KS, kx = tap%KS;
  int ic = ch*32+icq;
  float v = (ic<IC)? src[((oc*IC+ic)*KS+ky)*KS+kx] : 0.f;
  dst[idx] = f2b(v);
}

// ---------------- mask reductions ----------------
__global__ void flags_kernel(const int* __restrict__ masks, int* __restrict__ flags){
  __shared__ int red[256];
  int b = blockIdx.x; int acc=0;
  const int* m = masks + b*HWSZ;
  for(int i=threadIdx.x;i<HWSZ;i+=256) acc |= (m[i]>0)?1:0;
  red[threadIdx.x]=acc; __syncthreads();
  for(int s=128;s>0;s>>=1){ if(threadIdx.x<s) red[threadIdx.x]|=red[threadIdx.x+s]; __syncthreads(); }
  if(threadIdx.x==0) flags[b]=red[0];
}

__global__ void obs_kernel(const int* __restrict__ masks, const int* __restrict__ flags,
                           float* __restrict__ out){
  int p = blockIdx.x*256+threadIdx.x;
  if(p>=NPIX) return;
  int n = p>>16, hw = p&65535;
  int s=0;
  #pragma unroll
  for(int t=0;t<4;t++) s += masks[((n*4+t)<<16)+hw]*flags[n*4+t];
  out[p]=(float)s;
}

// ---------------- GRU (fp32 compute, bf16 state out) ----------------
__launch_bounds__(256)
__global__ void gru_kernel(const float* __restrict__ feat, const int* __restrict__ masks,
                           const float* __restrict__ Wt, const float* __restrict__ bih,
                           const float* __restrict__ bhh, unsigned short* __restrict__ S){
  __shared__ __align__(16) float axs[192][32];   // 24576 B
  __shared__ __align__(16) float wsm[16*384];    // 24576 B
  const int tid = threadIdx.x;
  const int p0 = blockIdx.x*32;
  const int n = p0>>16, hw0 = p0&65535;
  const int pxg = tid&7, jg = tid>>3;
  const int px0 = pxg*4, j0 = jg*4;

  for(int i=tid;i<128*32;i+=256) (&axs[64][0])[i]=0.f;

  for(int t=0;t<4;t++){
    __syncthreads();
    for(int i=tid;i<32*16;i+=256){
      int c4 = i&15, px = i>>4;
      float4 v = *(const float4*)&feat[ (size_t)(((n*4+t)<<16)|(hw0+px))*64 + c4*4 ];
      axs[c4*4+0][px]=v.x; axs[c4*4+1][px]=v.y; axs[c4*4+2][px]=v.z; axs[c4*4+3][px]=v.w;
    }

    float air[4][4], aiz[4][4], ain[4][4], ahr[4][4], ahz[4][4], ahn[4][4];
    #pragma unroll
    for(int p=0;p<4;p++)
      #pragma unroll
      for(int c=0;c<4;c++){ air[p][c]=0.f;aiz[p][c]=0.f;ain[p][c]=0.f;
                            ahr[p][c]=0.f;ahz[p][c]=0.f;ahn[p][c]=0.f; }

    #pragma unroll 1
    for(int ch=0;ch<4;ch++){
      __syncthreads();
      { const float4* src = (const float4*)(Wt + ch*16*384);
        float4* dst = (float4*)wsm;
        #pragma unroll
        for(int i=0;i<6;i++) dst[tid+i*256]=src[tid+i*256]; }
      __syncthreads();
      #pragma unroll
      for(int kk=0;kk<16;kk++){
        const float4 a = *(const float4*)&axs[ch*16+kk][px0];
        const float4* wrow = (const float4*)&wsm[kk*384];
        const float4 wr = wrow[jg], wz = wrow[32+jg], wn = wrow[64+jg];
        const float av[4]={a.x,a.y,a.z,a.w};
        #pragma unroll
        for(int p=0;p<4;p++){
          air[p][0]+=av[p]*wr.x; air[p][1]+=av[p]*wr.y; air[p][2]+=av[p]*wr.z; air[p][3]+=av[p]*wr.w;
          aiz[p][0]+=av[p]*wz.x; aiz[p][1]+=av[p]*wz.y; aiz[p][2]+=av[p]*wz.z; aiz[p][3]+=av[p]*wz.w;
          ain[p][0]+=av[p]*wn.x; ain[p][1]+=av[p]*wn.y; ain[p][2]+=av[p]*wn.z; ain[p][3]+=av[p]*wn.w;
        }
      }
    }
    #pragma unroll 1
    for(int ch=4;ch<12;ch++){
      __syncthreads();
      { const float4* src = (const float4*)(Wt + ch*16*384);
        float4* dst = (float4*)wsm;
        #pragma unroll
        for(int i=0;i<6;i++) dst[tid+i*256]=src[tid+i*256]; }
      __syncthreads();
      #pragma unroll
      for(int kk=0;kk<16;kk++){
        const float4 a = *(const float4*)&axs[ch*16+kk][px0];
        const float4* wrow = (const float4*)&wsm[kk*384];
        const float4 wr = wrow[jg], wz = wrow[32+jg], wn = wrow[64+jg];
        const float av[4]={a.x,a.y,a.z,a.w};
        #pragma unroll
        for(int p=0;p<4;p++){
          ahr[p][0]+=av[p]*wr.x; ahr[p][1]+=av[p]*wr.y; ahr[p][2]+=av[p]*wr.z; ahr[p][3]+=av[p]*wr.w;
          ahz[p][0]+=av[p]*wz.x; ahz[p][1]+=av[p]*wz.y; ahz[p][2]+=av[p]*wz.z; ahz[p][3]+=av[p]*wz.w;
          ahn[p][0]+=av[p]*wn.x; ahn[p][1]+=av[p]*wn.y; ahn[p][2]+=av[p]*wn.z; ahn[p][3]+=av[p]*wn.w;
        }
      }
    }
    __syncthreads();

    int ml[4];
    #pragma unroll
    for(int p=0;p<4;p++) ml[p]=masks[((n*4+t)<<16)+hw0+px0+p];
    #pragma unroll
    for(int c=0;c<4;c++){
      int j=j0+c;
      float br  = bih[j]     + bhh[j];
      float bz  = bih[128+j] + bhh[128+j];
      float bin = bih[256+j];
      float bhn = bhh[256+j];
      float4 h4 = *(const float4*)&axs[64+j][px0];
      float hold[4]={h4.x,h4.y,h4.z,h4.w};
      float hnew[4];
      #pragma unroll
      for(int p=0;p<4;p++){
        float r  = sigmf(air[p][c]+ahr[p][c]+br);
        float z  = sigmf(aiz[p][c]+ahz[p][c]+bz);
        float nn = tanhf2(ain[p][c]+bin + r*(ahn[p][c]+bhn));
        float h2 = (1.f-z)*nn + z*hold[p];
        hnew[p] = (ml[p]>0)? h2 : hold[p];
      }
      float4 hv={hnew[0],hnew[1],hnew[2],hnew[3]};
      *(float4*)&axs[64+j][px0]=hv;
    }
  }
  __syncthreads();
  // write state NHWC bf16
  for(int i=tid;i<32*32;i+=256){
    int c4=i&31, px=i>>5;
    ushort4 u;
    u.x=f2b(axs[64+c4*4+0][px]); u.y=f2b(axs[64+c4*4+1][px]);
    u.z=f2b(axs[64+c4*4+2][px]); u.w=f2b(axs[64+c4*4+3][px]);
    *(ushort4*)&S[(size_t)(p0+px)*128 + c4*4]=u;
  }
}

// ---------------- MFMA implicit-GEMM conv (NHWC bf16 in, fp32 out + BN partials) ----------------
// block = 128-px row segment x OC. 4 waves, wave w owns px [w*32, w*32+32).
template<int IC,int ICP,int OC,int KS>
__launch_bounds__(256)
__global__ void mconv(const unsigned short* __restrict__ in, const unsigned short* __restrict__ Wb,
                      float* __restrict__ out, float* __restrict__ partials){
  constexpr int P=KS/2, ROWS=128+KS-1, LDR=ICP+8, ICC=ICP/32, NT=OC/16, C8=ICP/8;
  __shared__ __align__(16) unsigned short lds[ROWS*LDR];
  const int tid=threadIdx.x;
  const int wave=tid>>6, lane=tid&63, l15=lane&15, quad=lane>>4;
  const int p0=blockIdx.x*128;
  const int n=p0>>16; const int hw0=p0&65535; const int y0=hw0>>8, x0=hw0&255;

  f32x4 acc[2][NT];
  #pragma unroll
  for(int mt=0;mt<2;mt++)
    #pragma unroll
    for(int nn=0;nn<NT;nn++){ f32x4 z={0.f,0.f,0.f,0.f}; acc[mt][nn]=z; }

  for(int ky=0;ky<KS;ky++){
    int ys=y0+ky-P;
    if(ys<0||ys>255) continue;          // uniform across block
    __syncthreads();
    for(int i=tid;i<ROWS*C8;i+=256){
      int c8=i%C8, px=i/C8;
      int xg=x0-P+px;
      float4 v={0.f,0.f,0.f,0.f};
      if(xg>=0 && xg<256 && c8*8<IC)
        v = *(const float4*)(in + (size_t)(((n<<16)|(ys<<8))+xg)*IC + c8*8);
      *(float4*)&lds[px*LDR + c8*8] = v;
    }
    __syncthreads();
    for(int kx=0;kx<KS;kx++){
      const int tap = ky*KS+kx;
      #pragma unroll
      for(int ch=0;ch<ICC;ch++){
        short8 a0 = *(const short8*)&lds[(wave*32 +      l15 + kx)*LDR + ch*32 + quad*8];
        short8 a1 = *(const short8*)&lds[(wave*32 + 16 + l15 + kx)*LDR + ch*32 + quad*8];
        const unsigned short* bp = Wb + ((size_t)((tap*ICC+ch)*OC + l15)<<5) + quad*8;
        #pragma unroll
        for(int nn=0;nn<NT;nn++){
          short8 b = *(const short8*)(bp + (nn<<9));
          acc[0][nn]=__builtin_amdgcn_mfma_f32_16x16x32_bf16(a0,b,acc[0][nn],0,0,0);
          acc[1][nn]=__builtin_amdgcn_mfma_f32_16x16x32_bf16(a1,b,acc[1][nn],0,0,0);
        }
      }
    }
  }
  __syncthreads();

  // raw fp32 out: D layout col(oc)=l15, row(px)=quad*4+reg
  #pragma unroll
  for(int mt=0;mt<2;mt++){
    int pxb = p0 + wave*32 + mt*16 + quad*4;
    #pragma unroll
    for(int nn=0;nn<NT;nn++){
      int oc = nn*16 + l15;
      #pragma unroll
      for(int r=0;r<4;r++)
        out[(size_t)(pxb+r)*OC + oc] = acc[mt][nn][r];
    }
  }

  // BN partials (reuse lds as float scratch: 2*16*OC floats)
  float* ps=(float*)lds;
  int row16 = wave*4+quad;
  #pragma unroll
  for(int nn=0;nn<NT;nn++){
    float s1=0.f,s2=0.f;
    #pragma unroll
    for(int mt=0;mt<2;mt++)
      #pragma unroll
      for(int r=0;r<4;r++){ float v=acc[mt][nn][r]; s1+=v; s2+=v*v; }
    ps[row16*OC + nn*16+l15]=s1;
    ps[(16+row16)*OC + nn*16+l15]=s2;
  }
  __syncthreads();
  if(tid<OC){
    float t1=0.f,t2=0.f;
    #pragma unroll
    for(int g=0;g<16;g++){ t1+=ps[g*OC+tid]; t2+=ps[(16+g)*OC+tid]; }
    partials[(size_t)blockIdx.x*2*OC+tid]=t1;
    partials[(size_t)blockIdx.x*2*OC+OC+tid]=t2;
  }
}

// ---------------- BN stats finalize ----------------
__global__ void stats_kernel(const float* __restrict__ partials, const float* __restrict__ g,
                             const float* __restrict__ b, float2* __restrict__ stats, int OC, int NB){
  __shared__ float r1[256], r2[256];
  int oc=blockIdx.x; int tid=threadIdx.x;
  float s1=0.f,s2=0.f;
  for(int bl=tid;bl<NB;bl+=256){ s1+=partials[(size_t)bl*2*OC+oc]; s2+=partials[(size_t)bl*2*OC+OC+oc]; }
  r1[tid]=s1;r2[tid]=s2; __syncthreads();
  for(int s=128;s>0;s>>=1){ if(tid<s){r1[tid]+=r1[tid+s]; r2[tid]+=r2[tid+s];} __syncthreads(); }
  if(tid==0){
    float mean=r1[0]*(1.f/131072.f);
    float var =r2[0]*(1.f/131072.f)-mean*mean;
    float sc=g[oc]*rsqrtf(var+1e-5f);
    float2 st; st.x=sc; st.y=b[oc]-mean*sc;
    stats[oc]=st;
  }
}

// BN+ReLU, fp32 -> bf16 (input to next MFMA conv)
__global__ void bnrelu_bf16(const float* __restrict__ src, unsigned short* __restrict__ dst,
                            const float2* __restrict__ stats, int OC4, int total4){
  for(int i=blockIdx.x*256+threadIdx.x;i<total4;i+=gridDim.x*256){
    int c4=i%OC4;
    float4 v=((const float4*)src)[i];
    float2 s0=stats[c4*4+0],s1=stats[c4*4+1],s2=stats[c4*4+2],s3=stats[c4*4+3];
    ushort4 u;
    u.x=f2b(fmaxf(0.f,v.x*s0.x+s0.y));
    u.y=f2b(fmaxf(0.f,v.y*s1.x+s1.y));
    u.z=f2b(fmaxf(0.f,v.z*s2.x+s2.y));
    u.w=f2b(fmaxf(0.f,v.w*s3.x+s3.y));
    ((ushort4*)dst)[i]=u;
  }
}

// BN+ReLU fp32 in-place (for obj2 input)
__global__ void bnrelu_kernel(float* __restrict__ buf, const float2* __restrict__ stats,
                              int OC4, int total4){
  for(int i=blockIdx.x*256+threadIdx.x;i<total4;i+=gridDim.x*256){
    int c4=i%OC4;
    float4 v=((float4*)buf)[i];
    float2 s0=stats[c4*4+0],s1=stats[c4*4+1],s2=stats[c4*4+2],s3=stats[c4*4+3];
    v.x=fmaxf(0.f,v.x*s0.x+s0.y);
    v.y=fmaxf(0.f,v.y*s1.x+s1.y);
    v.z=fmaxf(0.f,v.z*s2.x+s2.y);
    v.w=fmaxf(0.f,v.w*s3.x+s3.y);
    ((float4*)buf)[i]=v;
  }
}

// ---------------- final 1x1 conv 48->20, NCHW out + bias ----------------
__global__ void obj2_kernel(const float* __restrict__ in, const float* __restrict__ w,
                            const float* __restrict__ bias, float* __restrict__ out){
  __shared__ float wsm[20*48];
  __shared__ float bs[20];
  int tid=threadIdx.x;
  for(int i=tid;i<20*48;i+=256) wsm[i]=w[i];
  if(tid<20) bs[tid]=bias[tid];
  __syncthreads();
  int p=blockIdx.x*256+tid;
  int n=p>>16, hw=p&65535;
  float x[48];
  #pragma unroll
  for(int i=0;i<12;i++) *(float4*)&x[i*4]=*(const float4*)&in[(size_t)p*48+i*4];
  #pragma unroll
  for(int o=0;o<20;o++){
    float s=bs[o];
    #pragma unroll
    for(int c=0;c<48;c++) s+=x[c]*wsm[o*48+c];
    out[(size_t)((n*20+o)<<16)+hw]=s;
  }
}

extern "C" void kernel_launch(void* const* d_in, const int* in_sizes, int n_in,
                              void* d_out, int out_size, void* d_ws, size_t ws_size,
                              hipStream_t stream) {
  const float* feat = (const float*)d_in[0];
  const int*   masks= (const int*)  d_in[1];
  const float* w_ih = (const float*)d_in[2];
  const float* w_hh = (const float*)d_in[3];
  const float* b_ih = (const float*)d_in[4];
  const float* b_hh = (const float*)d_in[5];
  const float* c1w  = (const float*)d_in[6];
  const float* bn1g = (const float*)d_in[7];  const float* bn1b=(const float*)d_in[8];
  const float* c2w  = (const float*)d_in[9];
  const float* bn2g = (const float*)d_in[10]; const float* bn2b=(const float*)d_in[11];
  const float* c3w  = (const float*)d_in[12];
  const float* bn3g = (const float*)d_in[13]; const float* bn3b=(const float*)d_in[14];
  const float* o1w  = (const float*)d_in[15];
  const float* bn4g = (const float*)d_in[16]; const float* bn4b=(const float*)d_in[17];
  const float* o2w  = (const float*)d_in[18]; const float* o2b =(const float*)d_in[19];

  char* ws = (char*)d_ws;
  // fp32 activation region (A1/A2/A3/A4 all alias here; each dead before next write)
  float* Afp      = (float*)(ws + 0);                  // 67108864 B
  // bf16 region: S (conv1 in), later A2b / A3b
  unsigned short* Sb  = (unsigned short*)(ws + 67108864);   // 33554432 B
  unsigned short* A2b = (unsigned short*)(ws + 67108864);
  unsigned short* A3b = (unsigned short*)(ws + 67108864);
  unsigned short* A1b = (unsigned short*)(ws + 100663296);  // 33554432 B
  unsigned short* W1b = (unsigned short*)(ws + 134217728);  // 1605632 B
  unsigned short* W2b = (unsigned short*)(ws + 135823360);  // 147456 B
  unsigned short* W3b = (unsigned short*)(ws + 135970816);  // 55296 B
  unsigned short* W4b = (unsigned short*)(ws + 136026112);  // 55296 B
  float* WtG      = (float*)(ws + 136081408);               // 294912 B
  float* partials = (float*)(ws + 136376320);               // 1048576 B
  float2* stats   = (float2*)(ws + 137424896);              // 1024 B
  int*   flags    = (int*)  (ws + 137425920);               // 32 B

  float* semmap = (float*)d_out;                 // [2][20][256][256]
  float* obsout = (float*)d_out + 2621440;       // [2][256][256] as float

  prep_gru_w<<<288,256,0,stream>>>(w_ih,w_hh,WtG);
  prep_conv_w<<<(49*4*128*32+255)/256,256,0,stream>>>(c1w,W1b,128,4,128,7,49*4*128*32);
  prep_conv_w<<<(9*4*64*32 +255)/256,256,0,stream>>>(c2w,W2b,128,4,64,3,9*4*64*32);
  prep_conv_w<<<(9*2*48*32 +255)/256,256,0,stream>>>(c3w,W3b,64,2,48,3,9*2*48*32);
  prep_conv_w<<<(9*2*48*32 +255)/256,256,0,stream>>>(o1w,W4b,48,2,48,3,9*2*48*32);

  flags_kernel<<<8,256,0,stream>>>(masks,flags);
  obs_kernel<<<512,256,0,stream>>>(masks,flags,obsout);

  gru_kernel<<<4096,256,0,stream>>>(feat,masks,WtG,b_ih,b_hh,Sb);

  mconv<128,128,128,7><<<1024,256,0,stream>>>(Sb,W1b,Afp,partials);
  stats_kernel<<<128,256,0,stream>>>(partials,bn1g,bn1b,stats,128,1024);
  bnrelu_bf16<<<4096,256,0,stream>>>(Afp,A1b,stats,32,NPIX*128/4);

  mconv<128,128,64,3><<<1024,256,0,stream>>>(A1b,W2b,Afp,partials);
  stats_kernel<<<64,256,0,stream>>>(partials,bn2g,bn2b,stats,64,1024);
  bnrelu_bf16<<<4096,256,0,stream>>>(Afp,A2b,stats,16,NPIX*64/4);

  mconv<64,64,48,3><<<1024,256,0,stream>>>(A2b,W3b,Afp,partials);
  stats_kernel<<<48,256,0,stream>>>(partials,bn3g,bn3b,stats,48,1024);
  bnrelu_bf16<<<4096,256,0,stream>>>(Afp,A3b,stats,12,NPIX*48/4);

  mconv<48,64,48,3><<<1024,256,0,stream>>>(A3b,W4b,Afp,partials);
  stats_kernel<<<48,256,0,stream>>>(partials,bn4g,bn4b,stats,48,1024);
  bnrelu_kernel<<<4096,256,0,stream>>>(Afp,stats,12,NPIX*48/4);

  obj2_kernel<<<512,256,0,stream>>>(Afp,o2w,o2b,semmap);
}

// Round 4
// 1253.251 us; speedup vs baseline: 4.1210x; 2.1027x over previous
//
#include <hip/hip_runtime.h>
#include <hip/hip_bf16.h>
#include <math.h>

#define HWSZ 65536
#define NPIX 131072
#define LDA 208

typedef __attribute__((ext_vector_type(8))) short short8;
typedef __attribute__((ext_vector_type(4))) float f32x4;

__device__ __forceinline__ float sigmf(float x){ return 1.f/(1.f+__expf(-x)); }
__device__ __forceinline__ float tanhf2(float x){
  x = fminf(fmaxf(x,-15.f),15.f);
  float e = __expf(2.f*x);
  return (e-1.f)/(e+1.f);
}
__device__ __forceinline__ unsigned short f2b(float f){
  __hip_bfloat16 b = __float2bfloat16(f);
  return *(unsigned short*)&b;
}
__device__ __forceinline__ float b2f(unsigned short u){
  unsigned int v = ((unsigned int)u)<<16;
  return __uint_as_float(v);
}

// ---------------- weight prep ----------------
// GRU weights bf16: [kchunk(6)][col(384)][32 k] ; k = ch*32+kq; k<64 -> w_ih, else w_hh
__global__ void prep_gru_wb(const float* __restrict__ wih, const float* __restrict__ whh,
                            unsigned short* __restrict__ WG){
  int idx = blockIdx.x*256+threadIdx.x;
  if(idx >= 6*384*32) return;
  int kq = idx&31; int r = idx>>5;
  int c = r%384; int ch = r/384;
  int k = ch*32+kq;
  float v = (k<64) ? wih[c*64+k] : whh[c*128+(k-64)];
  WG[idx] = f2b(v);
}

// conv weights: [tap(ky*KS+kx)][chunk(ICP/32)][oc][32] bf16, zero-padded ic>=IC
__global__ void prep_conv_w(const float* __restrict__ src, unsigned short* __restrict__ dst,
                            int IC, int ICC, int OC, int KS, int total){
  int idx = blockIdx.x*256+threadIdx.x;
  if(idx>=total) return;
  int icq = idx&31; int r = idx>>5;
  int oc = r%OC; r/=OC;
  int ch = r%ICC; int tap = r/ICC;
  int ky = tap/KS, kx = tap%KS;
  int ic = ch*32+icq;
  float v = (ic<IC)? src[((oc*IC+ic)*KS+ky)*KS+kx] : 0.f;
  dst[idx] = f2b(v);
}

// ---------------- mask reductions ----------------
__global__ void flags_kernel(const int* __restrict__ masks, int* __restrict__ flags){
  __shared__ int red[256];
  int b = blockIdx.x; int acc=0;
  const int* m = masks + b*HWSZ;
  for(int i=threadIdx.x;i<HWSZ;i+=256) acc |= (m[i]>0)?1:0;
  red[threadIdx.x]=acc; __syncthreads();
  for(int s=128;s>0;s>>=1){ if(threadIdx.x<s) red[threadIdx.x]|=red[threadIdx.x+s]; __syncthreads(); }
  if(threadIdx.x==0) flags[b]=red[0];
}

__global__ void obs_kernel(const int* __restrict__ masks, const int* __restrict__ flags,
                           float* __restrict__ out){
  int p = blockIdx.x*256+threadIdx.x;
  if(p>=NPIX) return;
  int n = p>>16, hw = p&65535;
  int s=0;
  #pragma unroll
  for(int t=0;t<4;t++) s += masks[((n*4+t)<<16)+hw]*flags[n*4+t];
  out[p]=(float)s;
}

// ---------------- GRU via MFMA ----------------
// block = 64 px, 4 waves. Wave wv owns gate cols j in [wv*32, wv*32+32).
// LDS ax[px][LDA]: cols 0..63 = x_t (bf16), cols 64..191 = h (bf16).
__launch_bounds__(256,2)
__global__ void gru_mfma(const float* __restrict__ feat, const int* __restrict__ masks,
                         const unsigned short* __restrict__ WG,
                         const float* __restrict__ bih, const float* __restrict__ bhh,
                         unsigned short* __restrict__ S){
  __shared__ __align__(16) unsigned short ax[64*LDA];
  __shared__ int msk[64];
  const int tid=threadIdx.x, wv=tid>>6, lane=tid&63, l15=lane&15, quad=lane>>4;
  const int p0=blockIdx.x*64;
  const int n=p0>>16, hw0=p0&65535;

  // hoist biases (constant over t)
  float brv[2],bzv[2],binv[2],bhnv[2];
  #pragma unroll
  for(int g=0;g<2;g++){
    int j=wv*32+g*16+l15;
    brv[g]=bih[j]+bhh[j];
    bzv[g]=bih[128+j]+bhh[128+j];
    binv[g]=bih[256+j];
    bhnv[g]=bhh[256+j];
  }

  // zero h region
  float4 z4={0.f,0.f,0.f,0.f};
  for(int i=tid;i<64*16;i+=256){ int px=i>>4,c8=i&15; *(float4*)&ax[px*LDA+64+c8*8]=z4; }

  for(int t=0;t<4;t++){
    __syncthreads();   // prev gating writes / h-init visible; LDS x free to overwrite
    for(int i=tid;i<64*16;i+=256){
      int px=i>>4,c4=i&15;
      float4 v=*(const float4*)&feat[(size_t)(((n*4+t)<<16)|(hw0+px))*64 + c4*4];
      ushort4 u; u.x=f2b(v.x);u.y=f2b(v.y);u.z=f2b(v.z);u.w=f2b(v.w);
      *(ushort4*)&ax[px*LDA+c4*4]=u;
    }
    if(tid<64) msk[tid]=masks[((n*4+t)<<16)+hw0+tid];
    __syncthreads();

    f32x4 aR[4][2],aZ[4][2],aNX[4][2],aNH[4][2];
    #pragma unroll
    for(int mt=0;mt<4;mt++)
      #pragma unroll
      for(int g=0;g<2;g++){
        f32x4 zz={0.f,0.f,0.f,0.f};
        aR[mt][g]=zz; aZ[mt][g]=zz; aNX[mt][g]=zz; aNH[mt][g]=zz;
      }

    #pragma unroll
    for(int ch=0;ch<6;ch++){
      short8 a[4];
      #pragma unroll
      for(int mt=0;mt<4;mt++)
        a[mt]=*(const short8*)&ax[(mt*16+l15)*LDA + ch*32 + quad*8];
      const unsigned short* bb = WG + (((size_t)(ch*384 + wv*32 + l15))<<5) + quad*8;
      #pragma unroll
      for(int g=0;g<2;g++){
        short8 bR=*(const short8*)(bb + ((     g*16)<<5));
        short8 bZ=*(const short8*)(bb + ((128+g*16)<<5));
        short8 bN=*(const short8*)(bb + ((256+g*16)<<5));
        #pragma unroll
        for(int mt=0;mt<4;mt++){
          aR[mt][g]=__builtin_amdgcn_mfma_f32_16x16x32_bf16(a[mt],bR,aR[mt][g],0,0,0);
          aZ[mt][g]=__builtin_amdgcn_mfma_f32_16x16x32_bf16(a[mt],bZ,aZ[mt][g],0,0,0);
          if(ch<2)
            aNX[mt][g]=__builtin_amdgcn_mfma_f32_16x16x32_bf16(a[mt],bN,aNX[mt][g],0,0,0);
          else
            aNH[mt][g]=__builtin_amdgcn_mfma_f32_16x16x32_bf16(a[mt],bN,aNH[mt][g],0,0,0);
        }
      }
    }
    __syncthreads();   // all waves done reading h before owners overwrite

    // gating: C layout col=l15 (gate j), row(px in tile)=quad*4+reg
    #pragma unroll
    for(int g=0;g<2;g++){
      int j=wv*32+g*16+l15;
      #pragma unroll
      for(int mt=0;mt<4;mt++){
        #pragma unroll
        for(int r=0;r<4;r++){
          int px=mt*16+quad*4+r;
          float rg=sigmf(aR[mt][g][r]+brv[g]);
          float zg=sigmf(aZ[mt][g][r]+bzv[g]);
          float nn=tanhf2(aNX[mt][g][r]+binv[g]+rg*(aNH[mt][g][r]+bhnv[g]));
          unsigned short hu=ax[px*LDA+64+j];
          float hold=b2f(hu);
          float h2=(1.f-zg)*nn+zg*hold;
          ax[px*LDA+64+j] = (msk[px]>0)? f2b(h2) : hu;
        }
      }
    }
  }
  __syncthreads();
  // write state NHWC bf16
  for(int i=tid;i<64*16;i+=256){
    int px=i>>4,c8=i&15;
    *(float4*)&S[(size_t)(p0+px)*128 + c8*8] = *(float4*)&ax[px*LDA+64+c8*8];
  }
}

// ---------------- MFMA implicit-GEMM conv (NHWC bf16 in, fp32 out + BN partials) ----------------
template<int IC,int ICP,int OC,int KS>
__launch_bounds__(256)
__global__ void mconv(const unsigned short* __restrict__ in, const unsigned short* __restrict__ Wb,
                      float* __restrict__ out, float* __restrict__ partials){
  constexpr int P=KS/2, ROWS=128+KS-1, LDR=ICP+8, ICC=ICP/32, NT=OC/16, C8=ICP/8;
  __shared__ __align__(16) unsigned short lds[ROWS*LDR];
  const int tid=threadIdx.x;
  const int wave=tid>>6, lane=tid&63, l15=lane&15, quad=lane>>4;
  const int p0=blockIdx.x*128;
  const int n=p0>>16; const int hw0=p0&65535; const int y0=hw0>>8, x0=hw0&255;

  f32x4 acc[2][NT];
  #pragma unroll
  for(int mt=0;mt<2;mt++)
    #pragma unroll
    for(int nn=0;nn<NT;nn++){ f32x4 z={0.f,0.f,0.f,0.f}; acc[mt][nn]=z; }

  for(int ky=0;ky<KS;ky++){
    int ys=y0+ky-P;
    if(ys<0||ys>255) continue;          // uniform across block
    __syncthreads();
    for(int i=tid;i<ROWS*C8;i+=256){
      int c8=i%C8, px=i/C8;
      int xg=x0-P+px;
      float4 v={0.f,0.f,0.f,0.f};
      if(xg>=0 && xg<256 && c8*8<IC)
        v = *(const float4*)(in + (size_t)(((n<<16)|(ys<<8))+xg)*IC + c8*8);
      *(float4*)&lds[px*LDR + c8*8] = v;
    }
    __syncthreads();
    for(int kx=0;kx<KS;kx++){
      const int tap = ky*KS+kx;
      #pragma unroll
      for(int ch=0;ch<ICC;ch++){
        short8 a0 = *(const short8*)&lds[(wave*32 +      l15 + kx)*LDR + ch*32 + quad*8];
        short8 a1 = *(const short8*)&lds[(wave*32 + 16 + l15 + kx)*LDR + ch*32 + quad*8];
        const unsigned short* bp = Wb + ((size_t)((tap*ICC+ch)*OC + l15)<<5) + quad*8;
        #pragma unroll
        for(int nn=0;nn<NT;nn++){
          short8 b = *(const short8*)(bp + (nn<<9));
          acc[0][nn]=__builtin_amdgcn_mfma_f32_16x16x32_bf16(a0,b,acc[0][nn],0,0,0);
          acc[1][nn]=__builtin_amdgcn_mfma_f32_16x16x32_bf16(a1,b,acc[1][nn],0,0,0);
        }
      }
    }
  }
  __syncthreads();

  #pragma unroll
  for(int mt=0;mt<2;mt++){
    int pxb = p0 + wave*32 + mt*16 + quad*4;
    #pragma unroll
    for(int nn=0;nn<NT;nn++){
      int oc = nn*16 + l15;
      #pragma unroll
      for(int r=0;r<4;r++)
        out[(size_t)(pxb+r)*OC + oc] = acc[mt][nn][r];
    }
  }

  float* ps=(float*)lds;
  int row16 = wave*4+quad;
  #pragma unroll
  for(int nn=0;nn<NT;nn++){
    float s1=0.f,s2=0.f;
    #pragma unroll
    for(int mt=0;mt<2;mt++)
      #pragma unroll
      for(int r=0;r<4;r++){ float v=acc[mt][nn][r]; s1+=v; s2+=v*v; }
    ps[row16*OC + nn*16+l15]=s1;
    ps[(16+row16)*OC + nn*16+l15]=s2;
  }
  __syncthreads();
  if(tid<OC){
    float t1=0.f,t2=0.f;
    #pragma unroll
    for(int g=0;g<16;g++){ t1+=ps[g*OC+tid]; t2+=ps[(16+g)*OC+tid]; }
    partials[(size_t)blockIdx.x*2*OC+tid]=t1;
    partials[(size_t)blockIdx.x*2*OC+OC+tid]=t2;
  }
}

// ---------------- BN stats finalize ----------------
__global__ void stats_kernel(const float* __restrict__ partials, const float* __restrict__ g,
                             const float* __restrict__ b, float2* __restrict__ stats, int OC, int NB){
  __shared__ float r1[256], r2[256];
  int oc=blockIdx.x; int tid=threadIdx.x;
  float s1=0.f,s2=0.f;
  for(int bl=tid;bl<NB;bl+=256){ s1+=partials[(size_t)bl*2*OC+oc]; s2+=partials[(size_t)bl*2*OC+OC+oc]; }
  r1[tid]=s1;r2[tid]=s2; __syncthreads();
  for(int s=128;s>0;s>>=1){ if(tid<s){r1[tid]+=r1[tid+s]; r2[tid]+=r2[tid+s];} __syncthreads(); }
  if(tid==0){
    float mean=r1[0]*(1.f/131072.f);
    float var =r2[0]*(1.f/131072.f)-mean*mean;
    float sc=g[oc]*rsqrtf(var+1e-5f);
    float2 st; st.x=sc; st.y=b[oc]-mean*sc;
    stats[oc]=st;
  }
}

__global__ void bnrelu_bf16(const float* __restrict__ src, unsigned short* __restrict__ dst,
                            const float2* __restrict__ stats, int OC4, int total4){
  for(int i=blockIdx.x*256+threadIdx.x;i<total4;i+=gridDim.x*256){
    int c4=i%OC4;
    float4 v=((const float4*)src)[i];
    float2 s0=stats[c4*4+0],s1=stats[c4*4+1],s2=stats[c4*4+2],s3=stats[c4*4+3];
    ushort4 u;
    u.x=f2b(fmaxf(0.f,v.x*s0.x+s0.y));
    u.y=f2b(fmaxf(0.f,v.y*s1.x+s1.y));
    u.z=f2b(fmaxf(0.f,v.z*s2.x+s2.y));
    u.w=f2b(fmaxf(0.f,v.w*s3.x+s3.y));
    ((ushort4*)dst)[i]=u;
  }
}

__global__ void bnrelu_kernel(float* __restrict__ buf, const float2* __restrict__ stats,
                              int OC4, int total4){
  for(int i=blockIdx.x*256+threadIdx.x;i<total4;i+=gridDim.x*256){
    int c4=i%OC4;
    float4 v=((float4*)buf)[i];
    float2 s0=stats[c4*4+0],s1=stats[c4*4+1],s2=stats[c4*4+2],s3=stats[c4*4+3];
    v.x=fmaxf(0.f,v.x*s0.x+s0.y);
    v.y=fmaxf(0.f,v.y*s1.x+s1.y);
    v.z=fmaxf(0.f,v.z*s2.x+s2.y);
    v.w=fmaxf(0.f,v.w*s3.x+s3.y);
    ((float4*)buf)[i]=v;
  }
}

// ---------------- final 1x1 conv 48->20, NCHW out + bias ----------------
__global__ void obj2_kernel(const float* __restrict__ in, const float* __restrict__ w,
                            const float* __restrict__ bias, float* __restrict__ out){
  __shared__ float wsm[20*48];
  __shared__ float bs[20];
  int tid=threadIdx.x;
  for(int i=tid;i<20*48;i+=256) wsm[i]=w[i];
  if(tid<20) bs[tid]=bias[tid];
  __syncthreads();
  int p=blockIdx.x*256+tid;
  int n=p>>16, hw=p&65535;
  float x[48];
  #pragma unroll
  for(int i=0;i<12;i++) *(float4*)&x[i*4]=*(const float4*)&in[(size_t)p*48+i*4];
  #pragma unroll
  for(int o=0;o<20;o++){
    float s=bs[o];
    #pragma unroll
    for(int c=0;c<48;c++) s+=x[c]*wsm[o*48+c];
    out[(size_t)((n*20+o)<<16)+hw]=s;
  }
}

extern "C" void kernel_launch(void* const* d_in, const int* in_sizes, int n_in,
                              void* d_out, int out_size, void* d_ws, size_t ws_size,
                              hipStream_t stream) {
  const float* feat = (const float*)d_in[0];
  const int*   masks= (const int*)  d_in[1];
  const float* w_ih = (const float*)d_in[2];
  const float* w_hh = (const float*)d_in[3];
  const float* b_ih = (const float*)d_in[4];
  const float* b_hh = (const float*)d_in[5];
  const float* c1w  = (const float*)d_in[6];
  const float* bn1g = (const float*)d_in[7];  const float* bn1b=(const float*)d_in[8];
  const float* c2w  = (const float*)d_in[9];
  const float* bn2g = (const float*)d_in[10]; const float* bn2b=(const float*)d_in[11];
  const float* c3w  = (const float*)d_in[12];
  const float* bn3g = (const float*)d_in[13]; const float* bn3b=(const float*)d_in[14];
  const float* o1w  = (const float*)d_in[15];
  const float* bn4g = (const float*)d_in[16]; const float* bn4b=(const float*)d_in[17];
  const float* o2w  = (const float*)d_in[18]; const float* o2b =(const float*)d_in[19];

  char* ws = (char*)d_ws;
  float* Afp      = (float*)(ws + 0);                       // 67108864 B
  unsigned short* Sb  = (unsigned short*)(ws + 67108864);   // 33554432 B (aliased A2b/A3b)
  unsigned short* A2b = (unsigned short*)(ws + 67108864);
  unsigned short* A3b = (unsigned short*)(ws + 67108864);
  unsigned short* A1b = (unsigned short*)(ws + 100663296);  // 33554432 B
  unsigned short* W1b = (unsigned short*)(ws + 134217728);  // 1605632 B
  unsigned short* W2b = (unsigned short*)(ws + 135823360);  // 147456 B
  unsigned short* W3b = (unsigned short*)(ws + 135970816);  // 55296 B
  unsigned short* W4b = (unsigned short*)(ws + 136026112);  // 55296 B
  unsigned short* WGb = (unsigned short*)(ws + 136081408);  // 147456 B
  float* partials = (float*)(ws + 136376320);               // 1048576 B
  float2* stats   = (float2*)(ws + 137424896);              // 1024 B
  int*   flags    = (int*)  (ws + 137425920);               // 32 B

  float* semmap = (float*)d_out;                 // [2][20][256][256]
  float* obsout = (float*)d_out + 2621440;       // [2][256][256] as float

  prep_gru_wb<<<288,256,0,stream>>>(w_ih,w_hh,WGb);
  prep_conv_w<<<(49*4*128*32+255)/256,256,0,stream>>>(c1w,W1b,128,4,128,7,49*4*128*32);
  prep_conv_w<<<(9*4*64*32 +255)/256,256,0,stream>>>(c2w,W2b,128,4,64,3,9*4*64*32);
  prep_conv_w<<<(9*2*48*32 +255)/256,256,0,stream>>>(c3w,W3b,64,2,48,3,9*2*48*32);
  prep_conv_w<<<(9*2*48*32 +255)/256,256,0,stream>>>(o1w,W4b,48,2,48,3,9*2*48*32);

  flags_kernel<<<8,256,0,stream>>>(masks,flags);
  obs_kernel<<<512,256,0,stream>>>(masks,flags,obsout);

  gru_mfma<<<2048,256,0,stream>>>(feat,masks,WGb,b_ih,b_hh,Sb);

  mconv<128,128,128,7><<<1024,256,0,stream>>>(Sb,W1b,Afp,partials);
  stats_kernel<<<128,256,0,stream>>>(partials,bn1g,bn1b,stats,128,1024);
  bnrelu_bf16<<<4096,256,0,stream>>>(Afp,A1b,stats,32,NPIX*128/4);

  mconv<128,128,64,3><<<1024,256,0,stream>>>(A1b,W2b,Afp,partials);
  stats_kernel<<<64,256,0,stream>>>(partials,bn2g,bn2b,stats,64,1024);
  bnrelu_bf16<<<4096,256,0,stream>>>(Afp,A2b,stats,16,NPIX*64/4);

  mconv<64,64,48,3><<<1024,256,0,stream>>>(A2b,W3b,Afp,partials);
  stats_kernel<<<48,256,0,stream>>>(partials,bn3g,bn3b,stats,48,1024);
  bnrelu_bf16<<<4096,256,0,stream>>>(Afp,A3b,stats,12,NPIX*48/4);

  mconv<48,64,48,3><<<1024,256,0,stream>>>(A3b,W4b,Afp,partials);
  stats_kernel<<<48,256,0,stream>>>(partials,bn4g,bn4b,stats,48,1024);
  bnrelu_kernel<<<4096,256,0,stream>>>(Afp,stats,12,NPIX*48/4);

  obj2_kernel<<<512,256,0,stream>>>(Afp,o2w,o2b,semmap);
}

// Round 5
// 976.540 us; speedup vs baseline: 5.2888x; 1.2834x over previous
//
#include <hip/hip_runtime.h>
#include <hip/hip_bf16.h>
#include <math.h>

#define HWSZ 65536
#define NPIX 131072
#define LDA 208

typedef __attribute__((ext_vector_type(8))) short short8;
typedef __attribute__((ext_vector_type(4))) float f32x4;

__device__ __forceinline__ float sigmf(float x){ return 1.f/(1.f+__expf(-x)); }
__device__ __forceinline__ float tanhf2(float x){
  x = fminf(fmaxf(x,-15.f),15.f);
  float e = __expf(2.f*x);
  return (e-1.f)/(e+1.f);
}
__device__ __forceinline__ unsigned short f2b(float f){
  __hip_bfloat16 b = __float2bfloat16(f);
  return *(unsigned short*)&b;
}
__device__ __forceinline__ float b2f(unsigned short u){
  unsigned int v = ((unsigned int)u)<<16;
  return __uint_as_float(v);
}

// ---------------- weight prep ----------------
__global__ void prep_gru_wb(const float* __restrict__ wih, const float* __restrict__ whh,
                            unsigned short* __restrict__ WG){
  int idx = blockIdx.x*256+threadIdx.x;
  if(idx >= 6*384*32) return;
  int kq = idx&31; int r = idx>>5;
  int c = r%384; int ch = r/384;
  int k = ch*32+kq;
  float v = (k<64) ? wih[c*64+k] : whh[c*128+(k-64)];
  WG[idx] = f2b(v);
}

// conv weights: [tap(ky*KS+kx)][chunk(ICP/32)][oc][32] bf16, zero-padded ic>=IC
__global__ void prep_conv_w(const float* __restrict__ src, unsigned short* __restrict__ dst,
                            int IC, int ICC, int OC, int KS, int total){
  int idx = blockIdx.x*256+threadIdx.x;
  if(idx>=total) return;
  int icq = idx&31; int r = idx>>5;
  int oc = r%OC; r/=OC;
  int ch = r%ICC; int tap = r/ICC;
  int ky = tap/KS, kx = tap%KS;
  int ic = ch*32+icq;
  float v = (ic<IC)? src[((oc*IC+ic)*KS+ky)*KS+kx] : 0.f;
  dst[idx] = f2b(v);
}

// ---------------- mask reductions ----------------
__global__ void flags_kernel(const int* __restrict__ masks, int* __restrict__ flags){
  __shared__ int red[256];
  int b = blockIdx.x; int acc=0;
  const int* m = masks + b*HWSZ;
  for(int i=threadIdx.x;i<HWSZ;i+=256) acc |= (m[i]>0)?1:0;
  red[threadIdx.x]=acc; __syncthreads();
  for(int s=128;s>0;s>>=1){ if(threadIdx.x<s) red[threadIdx.x]|=red[threadIdx.x+s]; __syncthreads(); }
  if(threadIdx.x==0) flags[b]=red[0];
}

__global__ void obs_kernel(const int* __restrict__ masks, const int* __restrict__ flags,
                           float* __restrict__ out){
  int p = blockIdx.x*256+threadIdx.x;
  if(p>=NPIX) return;
  int n = p>>16, hw = p&65535;
  int s=0;
  #pragma unroll
  for(int t=0;t<4;t++) s += masks[((n*4+t)<<16)+hw]*flags[n*4+t];
  out[p]=(float)s;
}

// ---------------- GRU via MFMA ----------------
__launch_bounds__(256,2)
__global__ void gru_mfma(const float* __restrict__ feat, const int* __restrict__ masks,
                         const unsigned short* __restrict__ WG,
                         const float* __restrict__ bih, const float* __restrict__ bhh,
                         unsigned short* __restrict__ S){
  __shared__ __align__(16) unsigned short ax[64*LDA];
  __shared__ int msk[64];
  const int tid=threadIdx.x, wv=tid>>6, lane=tid&63, l15=lane&15, quad=lane>>4;
  const int p0=blockIdx.x*64;
  const int n=p0>>16, hw0=p0&65535;

  float brv[2],bzv[2],binv[2],bhnv[2];
  #pragma unroll
  for(int g=0;g<2;g++){
    int j=wv*32+g*16+l15;
    brv[g]=bih[j]+bhh[j];
    bzv[g]=bih[128+j]+bhh[128+j];
    binv[g]=bih[256+j];
    bhnv[g]=bhh[256+j];
  }

  float4 z4={0.f,0.f,0.f,0.f};
  for(int i=tid;i<64*16;i+=256){ int px=i>>4,c8=i&15; *(float4*)&ax[px*LDA+64+c8*8]=z4; }

  for(int t=0;t<4;t++){
    __syncthreads();
    for(int i=tid;i<64*16;i+=256){
      int px=i>>4,c4=i&15;
      float4 v=*(const float4*)&feat[(size_t)(((n*4+t)<<16)|(hw0+px))*64 + c4*4];
      ushort4 u; u.x=f2b(v.x);u.y=f2b(v.y);u.z=f2b(v.z);u.w=f2b(v.w);
      *(ushort4*)&ax[px*LDA+c4*4]=u;
    }
    if(tid<64) msk[tid]=masks[((n*4+t)<<16)+hw0+tid];
    __syncthreads();

    f32x4 aR[4][2],aZ[4][2],aNX[4][2],aNH[4][2];
    #pragma unroll
    for(int mt=0;mt<4;mt++)
      #pragma unroll
      for(int g=0;g<2;g++){
        f32x4 zz={0.f,0.f,0.f,0.f};
        aR[mt][g]=zz; aZ[mt][g]=zz; aNX[mt][g]=zz; aNH[mt][g]=zz;
      }

    #pragma unroll
    for(int ch=0;ch<6;ch++){
      short8 a[4];
      #pragma unroll
      for(int mt=0;mt<4;mt++)
        a[mt]=*(const short8*)&ax[(mt*16+l15)*LDA + ch*32 + quad*8];
      const unsigned short* bb = WG + (((size_t)(ch*384 + wv*32 + l15))<<5) + quad*8;
      #pragma unroll
      for(int g=0;g<2;g++){
        short8 bR=*(const short8*)(bb + ((     g*16)<<5));
        short8 bZ=*(const short8*)(bb + ((128+g*16)<<5));
        short8 bN=*(const short8*)(bb + ((256+g*16)<<5));
        #pragma unroll
        for(int mt=0;mt<4;mt++){
          aR[mt][g]=__builtin_amdgcn_mfma_f32_16x16x32_bf16(a[mt],bR,aR[mt][g],0,0,0);
          aZ[mt][g]=__builtin_amdgcn_mfma_f32_16x16x32_bf16(a[mt],bZ,aZ[mt][g],0,0,0);
          if(ch<2)
            aNX[mt][g]=__builtin_amdgcn_mfma_f32_16x16x32_bf16(a[mt],bN,aNX[mt][g],0,0,0);
          else
            aNH[mt][g]=__builtin_amdgcn_mfma_f32_16x16x32_bf16(a[mt],bN,aNH[mt][g],0,0,0);
        }
      }
    }
    __syncthreads();

    #pragma unroll
    for(int g=0;g<2;g++){
      int j=wv*32+g*16+l15;
      #pragma unroll
      for(int mt=0;mt<4;mt++){
        #pragma unroll
        for(int r=0;r<4;r++){
          int px=mt*16+quad*4+r;
          float rg=sigmf(aR[mt][g][r]+brv[g]);
          float zg=sigmf(aZ[mt][g][r]+bzv[g]);
          float nn=tanhf2(aNX[mt][g][r]+binv[g]+rg*(aNH[mt][g][r]+bhnv[g]));
          unsigned short hu=ax[px*LDA+64+j];
          float hold=b2f(hu);
          float h2=(1.f-zg)*nn+zg*hold;
          ax[px*LDA+64+j] = (msk[px]>0)? f2b(h2) : hu;
        }
      }
    }
  }
  __syncthreads();
  for(int i=tid;i<64*16;i+=256){
    int px=i>>4,c8=i&15;
    *(float4*)&S[(size_t)(p0+px)*128 + c8*8] = *(float4*)&ax[px*LDA+64+c8*8];
  }
}

// ---------------- MFMA implicit-GEMM conv, 2x2 wave tiling + B software pipeline ----------------
// block = 128 px x OC. OC>=64: waves tile (M/2 x N/2); OC<64: waves tile M/4 x full N.
template<int IC,int ICP,int OC,int KS>
__launch_bounds__(256,3)
__global__ void mconv(const unsigned short* __restrict__ in, const unsigned short* __restrict__ Wb,
                      float* __restrict__ out, float* __restrict__ partials){
  constexpr int P=KS/2, ROWS=128+KS-1, LDR=ICP+8, ICC=ICP/32, C8=ICP/8;
  constexpr int WM = (OC>=64)?2:4;          // waves along M
  constexpr int WN = 4/WM;                  // waves along N
  constexpr int MT = 128/(WM*16);           // m-tiles per wave
  constexpr int OCW = OC/WN;                // oc span per wave
  constexpr int NTW = OCW/16;               // n-tiles per wave
  constexpr int NS = KS*ICC;                // K-steps per ky
  __shared__ __align__(16) unsigned short lds[ROWS*LDR];
  const int tid=threadIdx.x;
  const int wv=tid>>6, lane=tid&63, l15=lane&15, quad=lane>>4;
  const int wm=wv/WN, wn=wv%WN;
  const int p0=blockIdx.x*128;
  const int n=p0>>16; const int hw0=p0&65535; const int y0=hw0>>8, x0=hw0&255;

  f32x4 acc[MT][NTW];
  #pragma unroll
  for(int mt=0;mt<MT;mt++)
    #pragma unroll
    for(int nn=0;nn<NTW;nn++){ f32x4 z={0.f,0.f,0.f,0.f}; acc[mt][nn]=z; }

  for(int ky=0;ky<KS;ky++){
    int ys=y0+ky-P;
    if(ys<0||ys>255) continue;          // uniform across block
    __syncthreads();
    for(int i=tid;i<ROWS*C8;i+=256){
      int c8=i%C8, px=i/C8;
      int xg=x0-P+px;
      float4 v={0.f,0.f,0.f,0.f};
      if(xg>=0 && xg<256 && c8*8<IC)
        v = *(const float4*)(in + (size_t)(((n<<16)|(ys<<8))+xg)*IC + c8*8);
      *(float4*)&lds[px*LDR + c8*8] = v;
    }
    __syncthreads();

    // software-pipelined K loop: prefetch B for step s+1 during MFMAs of step s
    short8 Bn[NTW];
    {
      const unsigned short* bp = Wb + ((size_t)(((ky*KS+0)*ICC+0)*OC + wn*OCW + l15)<<5) + quad*8;
      #pragma unroll
      for(int nn=0;nn<NTW;nn++) Bn[nn]=*(const short8*)(bp + (nn<<9));
    }
    #pragma unroll
    for(int s=0;s<NS;s++){
      const int kx=s/ICC, ch=s%ICC;
      short8 Bc[NTW];
      #pragma unroll
      for(int nn=0;nn<NTW;nn++) Bc[nn]=Bn[nn];
      if(s+1<NS){
        const int kx2=(s+1)/ICC, ch2=(s+1)%ICC;
        const unsigned short* bp = Wb + ((size_t)(((ky*KS+kx2)*ICC+ch2)*OC + wn*OCW + l15)<<5) + quad*8;
        #pragma unroll
        for(int nn=0;nn<NTW;nn++) Bn[nn]=*(const short8*)(bp + (nn<<9));
      }
      short8 a[MT];
      #pragma unroll
      for(int mt=0;mt<MT;mt++)
        a[mt]=*(const short8*)&lds[(wm*(MT*16) + mt*16 + l15 + kx)*LDR + ch*32 + quad*8];
      #pragma unroll
      for(int mt=0;mt<MT;mt++)
        #pragma unroll
        for(int nn=0;nn<NTW;nn++)
          acc[mt][nn]=__builtin_amdgcn_mfma_f32_16x16x32_bf16(a[mt],Bc[nn],acc[mt][nn],0,0,0);
    }
  }
  __syncthreads();

  // raw fp32 out: D layout col(oc)=l15, row(px)=quad*4+reg
  #pragma unroll
  for(int mt=0;mt<MT;mt++){
    int pxb = p0 + wm*(MT*16) + mt*16 + quad*4;
    #pragma unroll
    for(int nn=0;nn<NTW;nn++){
      int oc = wn*OCW + nn*16 + l15;
      #pragma unroll
      for(int r=0;r<4;r++)
        out[(size_t)(pxb+r)*OC + oc] = acc[mt][nn][r];
    }
  }

  // BN partials (reuse lds as float scratch: 2 * (WM*4) * OC floats)
  float* ps=(float*)lds;
  constexpr int RPS = WM*4;
  int rps = wm*4+quad;
  #pragma unroll
  for(int nn=0;nn<NTW;nn++){
    float s1=0.f,s2=0.f;
    #pragma unroll
    for(int mt=0;mt<MT;mt++)
      #pragma unroll
      for(int r=0;r<4;r++){ float v=acc[mt][nn][r]; s1+=v; s2+=v*v; }
    ps[rps*OC + wn*OCW + nn*16+l15]=s1;
    ps[(RPS+rps)*OC + wn*OCW + nn*16+l15]=s2;
  }
  __syncthreads();
  if(tid<OC){
    float t1=0.f,t2=0.f;
    #pragma unroll
    for(int g=0;g<RPS;g++){ t1+=ps[g*OC+tid]; t2+=ps[(RPS+g)*OC+tid]; }
    partials[(size_t)blockIdx.x*2*OC+tid]=t1;
    partials[(size_t)blockIdx.x*2*OC+OC+tid]=t2;
  }
}

// ---------------- BN stats finalize ----------------
__global__ void stats_kernel(const float* __restrict__ partials, const float* __restrict__ g,
                             const float* __restrict__ b, float2* __restrict__ stats, int OC, int NB){
  __shared__ float r1[256], r2[256];
  int oc=blockIdx.x; int tid=threadIdx.x;
  float s1=0.f,s2=0.f;
  for(int bl=tid;bl<NB;bl+=256){ s1+=partials[(size_t)bl*2*OC+oc]; s2+=partials[(size_t)bl*2*OC+OC+oc]; }
  r1[tid]=s1;r2[tid]=s2; __syncthreads();
  for(int s=128;s>0;s>>=1){ if(tid<s){r1[tid]+=r1[tid+s]; r2[tid]+=r2[tid+s];} __syncthreads(); }
  if(tid==0){
    float mean=r1[0]*(1.f/131072.f);
    float var =r2[0]*(1.f/131072.f)-mean*mean;
    float sc=g[oc]*rsqrtf(var+1e-5f);
    float2 st; st.x=sc; st.y=b[oc]-mean*sc;
    stats[oc]=st;
  }
}

__global__ void bnrelu_bf16(const float* __restrict__ src, unsigned short* __restrict__ dst,
                            const float2* __restrict__ stats, int OC4, int total4){
  for(int i=blockIdx.x*256+threadIdx.x;i<total4;i+=gridDim.x*256){
    int c4=i%OC4;
    float4 v=((const float4*)src)[i];
    float2 s0=stats[c4*4+0],s1=stats[c4*4+1],s2=stats[c4*4+2],s3=stats[c4*4+3];
    ushort4 u;
    u.x=f2b(fmaxf(0.f,v.x*s0.x+s0.y));
    u.y=f2b(fmaxf(0.f,v.y*s1.x+s1.y));
    u.z=f2b(fmaxf(0.f,v.z*s2.x+s2.y));
    u.w=f2b(fmaxf(0.f,v.w*s3.x+s3.y));
    ((ushort4*)dst)[i]=u;
  }
}

__global__ void bnrelu_kernel(float* __restrict__ buf, const float2* __restrict__ stats,
                              int OC4, int total4){
  for(int i=blockIdx.x*256+threadIdx.x;i<total4;i+=gridDim.x*256){
    int c4=i%OC4;
    float4 v=((float4*)buf)[i];
    float2 s0=stats[c4*4+0],s1=stats[c4*4+1],s2=stats[c4*4+2],s3=stats[c4*4+3];
    v.x=fmaxf(0.f,v.x*s0.x+s0.y);
    v.y=fmaxf(0.f,v.y*s1.x+s1.y);
    v.z=fmaxf(0.f,v.z*s2.x+s2.y);
    v.w=fmaxf(0.f,v.w*s3.x+s3.y);
    ((float4*)buf)[i]=v;
  }
}

// ---------------- final 1x1 conv 48->20, NCHW out + bias ----------------
__global__ void obj2_kernel(const float* __restrict__ in, const float* __restrict__ w,
                            const float* __restrict__ bias, float* __restrict__ out){
  __shared__ float wsm[20*48];
  __shared__ float bs[20];
  int tid=threadIdx.x;
  for(int i=tid;i<20*48;i+=256) wsm[i]=w[i];
  if(tid<20) bs[tid]=bias[tid];
  __syncthreads();
  int p=blockIdx.x*256+tid;
  int n=p>>16, hw=p&65535;
  float x[48];
  #pragma unroll
  for(int i=0;i<12;i++) *(float4*)&x[i*4]=*(const float4*)&in[(size_t)p*48+i*4];
  #pragma unroll
  for(int o=0;o<20;o++){
    float s=bs[o];
    #pragma unroll
    for(int c=0;c<48;c++) s+=x[c]*wsm[o*48+c];
    out[(size_t)((n*20+o)<<16)+hw]=s;
  }
}

extern "C" void kernel_launch(void* const* d_in, const int* in_sizes, int n_in,
                              void* d_out, int out_size, void* d_ws, size_t ws_size,
                              hipStream_t stream) {
  const float* feat = (const float*)d_in[0];
  const int*   masks= (const int*)  d_in[1];
  const float* w_ih = (const float*)d_in[2];
  const float* w_hh = (const float*)d_in[3];
  const float* b_ih = (const float*)d_in[4];
  const float* b_hh = (const float*)d_in[5];
  const float* c1w  = (const float*)d_in[6];
  const float* bn1g = (const float*)d_in[7];  const float* bn1b=(const float*)d_in[8];
  const float* c2w  = (const float*)d_in[9];
  const float* bn2g = (const float*)d_in[10]; const float* bn2b=(const float*)d_in[11];
  const float* c3w  = (const float*)d_in[12];
  const float* bn3g = (const float*)d_in[13]; const float* bn3b=(const float*)d_in[14];
  const float* o1w  = (const float*)d_in[15];
  const float* bn4g = (const float*)d_in[16]; const float* bn4b=(const float*)d_in[17];
  const float* o2w  = (const float*)d_in[18]; const float* o2b =(const float*)d_in[19];

  char* ws = (char*)d_ws;
  float* Afp      = (float*)(ws + 0);                       // 67108864 B
  unsigned short* Sb  = (unsigned short*)(ws + 67108864);   // 33554432 B (aliased A2b/A3b)
  unsigned short* A2b = (unsigned short*)(ws + 67108864);
  unsigned short* A3b = (unsigned short*)(ws + 67108864);
  unsigned short* A1b = (unsigned short*)(ws + 100663296);  // 33554432 B
  unsigned short* W1b = (unsigned short*)(ws + 134217728);  // 1605632 B
  unsigned short* W2b = (unsigned short*)(ws + 135823360);  // 147456 B
  unsigned short* W3b = (unsigned short*)(ws + 135970816);  // 55296 B
  unsigned short* W4b = (unsigned short*)(ws + 136026112);  // 55296 B
  unsigned short* WGb = (unsigned short*)(ws + 136081408);  // 147456 B
  float* partials = (float*)(ws + 136376320);               // 1048576 B
  float2* stats   = (float2*)(ws + 137424896);              // 1024 B
  int*   flags    = (int*)  (ws + 137425920);               // 32 B

  float* semmap = (float*)d_out;                 // [2][20][256][256]
  float* obsout = (float*)d_out + 2621440;       // [2][256][256] as float

  prep_gru_wb<<<288,256,0,stream>>>(w_ih,w_hh,WGb);
  prep_conv_w<<<(49*4*128*32+255)/256,256,0,stream>>>(c1w,W1b,128,4,128,7,49*4*128*32);
  prep_conv_w<<<(9*4*64*32 +255)/256,256,0,stream>>>(c2w,W2b,128,4,64,3,9*4*64*32);
  prep_conv_w<<<(9*2*48*32 +255)/256,256,0,stream>>>(c3w,W3b,64,2,48,3,9*2*48*32);
  prep_conv_w<<<(9*2*48*32 +255)/256,256,0,stream>>>(o1w,W4b,48,2,48,3,9*2*48*32);

  flags_kernel<<<8,256,0,stream>>>(masks,flags);
  obs_kernel<<<512,256,0,stream>>>(masks,flags,obsout);

  gru_mfma<<<2048,256,0,stream>>>(feat,masks,WGb,b_ih,b_hh,Sb);

  mconv<128,128,128,7><<<1024,256,0,stream>>>(Sb,W1b,Afp,partials);
  stats_kernel<<<128,256,0,stream>>>(partials,bn1g,bn1b,stats,128,1024);
  bnrelu_bf16<<<4096,256,0,stream>>>(Afp,A1b,stats,32,NPIX*128/4);

  mconv<128,128,64,3><<<1024,256,0,stream>>>(A1b,W2b,Afp,partials);
  stats_kernel<<<64,256,0,stream>>>(partials,bn2g,bn2b,stats,64,1024);
  bnrelu_bf16<<<4096,256,0,stream>>>(Afp,A2b,stats,16,NPIX*64/4);

  mconv<64,64,48,3><<<1024,256,0,stream>>>(A2b,W3b,Afp,partials);
  stats_kernel<<<48,256,0,stream>>>(partials,bn3g,bn3b,stats,48,1024);
  bnrelu_bf16<<<4096,256,0,stream>>>(Afp,A3b,stats,12,NPIX*48/4);

  mconv<48,64,48,3><<<1024,256,0,stream>>>(A3b,W4b,Afp,partials);
  stats_kernel<<<48,256,0,stream>>>(partials,bn4g,bn4b,stats,48,1024);
  bnrelu_kernel<<<4096,256,0,stream>>>(Afp,stats,12,NPIX*48/4);

  obj2_kernel<<<512,256,0,stream>>>(Afp,o2w,o2b,semmap);
}

// Round 6
// 888.864 us; speedup vs baseline: 5.8105x; 1.0986x over previous
//
#include <hip/hip_runtime.h>
#include <hip/hip_bf16.h>
#include <math.h>

#define HWSZ 65536
#define NPIX 131072
#define LDA 208

typedef __attribute__((ext_vector_type(8))) short short8;
typedef __attribute__((ext_vector_type(4))) float f32x4;

__device__ __forceinline__ float sigmf(float x){ return 1.f/(1.f+__expf(-x)); }
__device__ __forceinline__ float tanhf2(float x){
  x = fminf(fmaxf(x,-15.f),15.f);
  float e = __expf(2.f*x);
  return (e-1.f)/(e+1.f);
}
__device__ __forceinline__ unsigned short f2b(float f){
  __hip_bfloat16 b = __float2bfloat16(f);
  return *(unsigned short*)&b;
}
__device__ __forceinline__ float b2f(unsigned short u){
  unsigned int v = ((unsigned int)u)<<16;
  return __uint_as_float(v);
}

// ---------------- weight prep ----------------
__global__ void prep_gru_wb(const float* __restrict__ wih, const float* __restrict__ whh,
                            unsigned short* __restrict__ WG){
  int idx = blockIdx.x*256+threadIdx.x;
  if(idx >= 6*384*32) return;
  int kq = idx&31; int r = idx>>5;
  int c = r%384; int ch = r/384;
  int k = ch*32+kq;
  float v = (k<64) ? wih[c*64+k] : whh[c*128+(k-64)];
  WG[idx] = f2b(v);
}

// conv weights: [tap(ky*KS+kx)][chunk(ICP/32)][oc][32] bf16, zero-padded ic>=IC
__global__ void prep_conv_w(const float* __restrict__ src, unsigned short* __restrict__ dst,
                            int IC, int ICC, int OC, int KS, int total){
  int idx = blockIdx.x*256+threadIdx.x;
  if(idx>=total) return;
  int icq = idx&31; int r = idx>>5;
  int oc = r%OC; r/=OC;
  int ch = r%ICC; int tap = r/ICC;
  int ky = tap/KS, kx = tap%KS;
  int ic = ch*32+icq;
  float v = (ic<IC)? src[((oc*IC+ic)*KS+ky)*KS+kx] : 0.f;
  dst[idx] = f2b(v);
}

// ---------------- mask reductions ----------------
__global__ void flags_kernel(const int* __restrict__ masks, int* __restrict__ flags){
  __shared__ int red[256];
  int b = blockIdx.x; int acc=0;
  const int* m = masks + b*HWSZ;
  for(int i=threadIdx.x;i<HWSZ;i+=256) acc |= (m[i]>0)?1:0;
  red[threadIdx.x]=acc; __syncthreads();
  for(int s=128;s>0;s>>=1){ if(threadIdx.x<s) red[threadIdx.x]|=red[threadIdx.x+s]; __syncthreads(); }
  if(threadIdx.x==0) flags[b]=red[0];
}

__global__ void obs_kernel(const int* __restrict__ masks, const int* __restrict__ flags,
                           float* __restrict__ out){
  int p = blockIdx.x*256+threadIdx.x;
  if(p>=NPIX) return;
  int n = p>>16, hw = p&65535;
  int s=0;
  #pragma unroll
  for(int t=0;t<4;t++) s += masks[((n*4+t)<<16)+hw]*flags[n*4+t];
  out[p]=(float)s;
}

// ---------------- GRU via MFMA ----------------
__launch_bounds__(256,2)
__global__ void gru_mfma(const float* __restrict__ feat, const int* __restrict__ masks,
                         const unsigned short* __restrict__ WG,
                         const float* __restrict__ bih, const float* __restrict__ bhh,
                         unsigned short* __restrict__ S){
  __shared__ __align__(16) unsigned short ax[64*LDA];
  __shared__ int msk[64];
  const int tid=threadIdx.x, wv=tid>>6, lane=tid&63, l15=lane&15, quad=lane>>4;
  const int p0=blockIdx.x*64;
  const int n=p0>>16, hw0=p0&65535;

  float brv[2],bzv[2],binv[2],bhnv[2];
  #pragma unroll
  for(int g=0;g<2;g++){
    int j=wv*32+g*16+l15;
    brv[g]=bih[j]+bhh[j];
    bzv[g]=bih[128+j]+bhh[128+j];
    binv[g]=bih[256+j];
    bhnv[g]=bhh[256+j];
  }

  float4 z4={0.f,0.f,0.f,0.f};
  for(int i=tid;i<64*16;i+=256){ int px=i>>4,c8=i&15; *(float4*)&ax[px*LDA+64+c8*8]=z4; }

  for(int t=0;t<4;t++){
    __syncthreads();
    for(int i=tid;i<64*16;i+=256){
      int px=i>>4,c4=i&15;
      float4 v=*(const float4*)&feat[(size_t)(((n*4+t)<<16)|(hw0+px))*64 + c4*4];
      ushort4 u; u.x=f2b(v.x);u.y=f2b(v.y);u.z=f2b(v.z);u.w=f2b(v.w);
      *(ushort4*)&ax[px*LDA+c4*4]=u;
    }
    if(tid<64) msk[tid]=masks[((n*4+t)<<16)+hw0+tid];
    __syncthreads();

    f32x4 aR[4][2],aZ[4][2],aNX[4][2],aNH[4][2];
    #pragma unroll
    for(int mt=0;mt<4;mt++)
      #pragma unroll
      for(int g=0;g<2;g++){
        f32x4 zz={0.f,0.f,0.f,0.f};
        aR[mt][g]=zz; aZ[mt][g]=zz; aNX[mt][g]=zz; aNH[mt][g]=zz;
      }

    #pragma unroll
    for(int ch=0;ch<6;ch++){
      short8 a[4];
      #pragma unroll
      for(int mt=0;mt<4;mt++)
        a[mt]=*(const short8*)&ax[(mt*16+l15)*LDA + ch*32 + quad*8];
      const unsigned short* bb = WG + (((size_t)(ch*384 + wv*32 + l15))<<5) + quad*8;
      #pragma unroll
      for(int g=0;g<2;g++){
        short8 bR=*(const short8*)(bb + ((     g*16)<<5));
        short8 bZ=*(const short8*)(bb + ((128+g*16)<<5));
        short8 bN=*(const short8*)(bb + ((256+g*16)<<5));
        #pragma unroll
        for(int mt=0;mt<4;mt++){
          aR[mt][g]=__builtin_amdgcn_mfma_f32_16x16x32_bf16(a[mt],bR,aR[mt][g],0,0,0);
          aZ[mt][g]=__builtin_amdgcn_mfma_f32_16x16x32_bf16(a[mt],bZ,aZ[mt][g],0,0,0);
          if(ch<2)
            aNX[mt][g]=__builtin_amdgcn_mfma_f32_16x16x32_bf16(a[mt],bN,aNX[mt][g],0,0,0);
          else
            aNH[mt][g]=__builtin_amdgcn_mfma_f32_16x16x32_bf16(a[mt],bN,aNH[mt][g],0,0,0);
        }
      }
    }
    __syncthreads();

    #pragma unroll
    for(int g=0;g<2;g++){
      int j=wv*32+g*16+l15;
      #pragma unroll
      for(int mt=0;mt<4;mt++){
        #pragma unroll
        for(int r=0;r<4;r++){
          int px=mt*16+quad*4+r;
          float rg=sigmf(aR[mt][g][r]+brv[g]);
          float zg=sigmf(aZ[mt][g][r]+bzv[g]);
          float nn=tanhf2(aNX[mt][g][r]+binv[g]+rg*(aNH[mt][g][r]+bhnv[g]));
          unsigned short hu=ax[px*LDA+64+j];
          float hold=b2f(hu);
          float h2=(1.f-zg)*nn+zg*hold;
          ax[px*LDA+64+j] = (msk[px]>0)? f2b(h2) : hu;
        }
      }
    }
  }
  __syncthreads();
  for(int i=tid;i<64*16;i+=256){
    int px=i>>4,c8=i&15;
    *(float4*)&S[(size_t)(p0+px)*128 + c8*8] = *(float4*)&ax[px*LDA+64+c8*8];
  }
}

// ---------------- MFMA implicit-GEMM conv ----------------
// block = 128 px x OC; TPB/64 waves tiled WM x WN; bf16 raw out + fp32 BN partials.
template<int IC,int ICP,int OC,int KS,int TPB,int WM,int WN>
__launch_bounds__(TPB, (TPB==512)?4:3)
__global__ void mconv(const unsigned short* __restrict__ in, const unsigned short* __restrict__ Wb,
                      unsigned short* __restrict__ out, float* __restrict__ partials){
  constexpr int P=KS/2, ROWS=128+KS-1, LDR=ICP+8, ICC=ICP/32, C8=ICP/8;
  constexpr int MT = 128/(WM*16);           // m-tiles per wave
  constexpr int OCW = OC/WN;                // oc span per wave
  constexpr int NTW = OCW/16;               // n-tiles per wave
  constexpr int NS = KS*ICC;                // K-steps per ky
  constexpr int RPS = WM*4;
  __shared__ __align__(16) unsigned short lds[ROWS*LDR];
  const int tid=threadIdx.x;
  const int wv=tid>>6, lane=tid&63, l15=lane&15, quad=lane>>4;
  const int wm=wv/WN, wn=wv%WN;
  const int p0=blockIdx.x*128;
  const int n=p0>>16; const int hw0=p0&65535; const int y0=hw0>>8, x0=hw0&255;

  f32x4 acc[MT][NTW];
  #pragma unroll
  for(int mt=0;mt<MT;mt++)
    #pragma unroll
    for(int nn=0;nn<NTW;nn++){ f32x4 z={0.f,0.f,0.f,0.f}; acc[mt][nn]=z; }

  for(int ky=0;ky<KS;ky++){
    int ys=y0+ky-P;
    if(ys<0||ys>255) continue;          // uniform across block
    __syncthreads();
    for(int i=tid;i<ROWS*C8;i+=TPB){
      int c8=i%C8, px=i/C8;
      int xg=x0-P+px;
      float4 v={0.f,0.f,0.f,0.f};
      if(xg>=0 && xg<256 && c8*8<IC)
        v = *(const float4*)(in + (size_t)(((n<<16)|(ys<<8))+xg)*IC + c8*8);
      *(float4*)&lds[px*LDR + c8*8] = v;
    }
    __syncthreads();

    // software-pipelined K loop: prefetch B for step s+1 during MFMAs of step s
    short8 Bn[NTW];
    {
      const unsigned short* bp = Wb + ((size_t)(((ky*KS+0)*ICC+0)*OC + wn*OCW + l15)<<5) + quad*8;
      #pragma unroll
      for(int nn=0;nn<NTW;nn++) Bn[nn]=*(const short8*)(bp + (nn<<9));
    }
    #pragma unroll
    for(int s=0;s<NS;s++){
      const int kx=s/ICC, ch=s%ICC;
      short8 Bc[NTW];
      #pragma unroll
      for(int nn=0;nn<NTW;nn++) Bc[nn]=Bn[nn];
      if(s+1<NS){
        const int kx2=(s+1)/ICC, ch2=(s+1)%ICC;
        const unsigned short* bp = Wb + ((size_t)(((ky*KS+kx2)*ICC+ch2)*OC + wn*OCW + l15)<<5) + quad*8;
        #pragma unroll
        for(int nn=0;nn<NTW;nn++) Bn[nn]=*(const short8*)(bp + (nn<<9));
      }
      short8 a[MT];
      #pragma unroll
      for(int mt=0;mt<MT;mt++)
        a[mt]=*(const short8*)&lds[(wm*(MT*16) + mt*16 + l15 + kx)*LDR + ch*32 + quad*8];
      #pragma unroll
      for(int mt=0;mt<MT;mt++)
        #pragma unroll
        for(int nn=0;nn<NTW;nn++)
          acc[mt][nn]=__builtin_amdgcn_mfma_f32_16x16x32_bf16(a[mt],Bc[nn],acc[mt][nn],0,0,0);
    }
  }
  __syncthreads();

  // raw bf16 out: D layout col(oc)=l15, row(px)=quad*4+reg
  #pragma unroll
  for(int mt=0;mt<MT;mt++){
    int pxb = p0 + wm*(MT*16) + mt*16 + quad*4;
    #pragma unroll
    for(int nn=0;nn<NTW;nn++){
      int oc = wn*OCW + nn*16 + l15;
      #pragma unroll
      for(int r=0;r<4;r++)
        out[(size_t)(pxb+r)*OC + oc] = f2b(acc[mt][nn][r]);
    }
  }

  // BN partials (reuse lds as float scratch: 2*RPS*OC floats)
  float* ps=(float*)lds;
  int rps = wm*4+quad;
  #pragma unroll
  for(int nn=0;nn<NTW;nn++){
    float s1=0.f,s2=0.f;
    #pragma unroll
    for(int mt=0;mt<MT;mt++)
      #pragma unroll
      for(int r=0;r<4;r++){ float v=acc[mt][nn][r]; s1+=v; s2+=v*v; }
    ps[rps*OC + wn*OCW + nn*16+l15]=s1;
    ps[(RPS+rps)*OC + wn*OCW + nn*16+l15]=s2;
  }
  __syncthreads();
  if(tid<OC){
    float t1=0.f,t2=0.f;
    #pragma unroll
    for(int g=0;g<RPS;g++){ t1+=ps[g*OC+tid]; t2+=ps[(RPS+g)*OC+tid]; }
    partials[(size_t)blockIdx.x*2*OC+tid]=t1;
    partials[(size_t)blockIdx.x*2*OC+OC+tid]=t2;
  }
}

// ---------------- BN stats finalize ----------------
__global__ void stats_kernel(const float* __restrict__ partials, const float* __restrict__ g,
                             const float* __restrict__ b, float2* __restrict__ stats, int OC, int NB){
  __shared__ float r1[256], r2[256];
  int oc=blockIdx.x; int tid=threadIdx.x;
  float s1=0.f,s2=0.f;
  for(int bl=tid;bl<NB;bl+=256){ s1+=partials[(size_t)bl*2*OC+oc]; s2+=partials[(size_t)bl*2*OC+OC+oc]; }
  r1[tid]=s1;r2[tid]=s2; __syncthreads();
  for(int s=128;s>0;s>>=1){ if(tid<s){r1[tid]+=r1[tid+s]; r2[tid]+=r2[tid+s];} __syncthreads(); }
  if(tid==0){
    float mean=r1[0]*(1.f/131072.f);
    float var =r2[0]*(1.f/131072.f)-mean*mean;
    float sc=g[oc]*rsqrtf(var+1e-5f);
    float2 st; st.x=sc; st.y=b[oc]-mean*sc;
    stats[oc]=st;
  }
}

// BN+ReLU, bf16 -> bf16 (8 channels per thread-iter)
__global__ void bnrelu_b2b(const unsigned short* __restrict__ src, unsigned short* __restrict__ dst,
                           const float2* __restrict__ stats, int OC8, int total8){
  for(int i=blockIdx.x*256+threadIdx.x;i<total8;i+=gridDim.x*256){
    int c8=i%OC8;
    float4 v=((const float4*)src)[i];
    const unsigned short* us=(const unsigned short*)&v;
    float4 o;
    unsigned short* od=(unsigned short*)&o;
    #pragma unroll
    for(int j=0;j<8;j++){
      float2 s=stats[c8*8+j];
      od[j]=f2b(fmaxf(0.f, b2f(us[j])*s.x+s.y));
    }
    ((float4*)dst)[i]=o;
  }
}

// ---------------- final 1x1 conv 48->20, bf16 in, NCHW fp32 out + bias ----------------
__global__ void obj2_kernel(const unsigned short* __restrict__ in, const float* __restrict__ w,
                            const float* __restrict__ bias, float* __restrict__ out){
  __shared__ float wsm[20*48];
  __shared__ float bs[20];
  int tid=threadIdx.x;
  for(int i=tid;i<20*48;i+=256) wsm[i]=w[i];
  if(tid<20) bs[tid]=bias[tid];
  __syncthreads();
  int p=blockIdx.x*256+tid;
  int n=p>>16, hw=p&65535;
  float x[48];
  #pragma unroll
  for(int i=0;i<6;i++){
    float4 v=*(const float4*)&in[(size_t)p*48+i*8];
    const unsigned short* us=(const unsigned short*)&v;
    #pragma unroll
    for(int j=0;j<8;j++) x[i*8+j]=b2f(us[j]);
  }
  #pragma unroll
  for(int o=0;o<20;o++){
    float s=bs[o];
    #pragma unroll
    for(int c=0;c<48;c++) s+=x[c]*wsm[o*48+c];
    out[(size_t)((n*20+o)<<16)+hw]=s;
  }
}

extern "C" void kernel_launch(void* const* d_in, const int* in_sizes, int n_in,
                              void* d_out, int out_size, void* d_ws, size_t ws_size,
                              hipStream_t stream) {
  const float* feat = (const float*)d_in[0];
  const int*   masks= (const int*)  d_in[1];
  const float* w_ih = (const float*)d_in[2];
  const float* w_hh = (const float*)d_in[3];
  const float* b_ih = (const float*)d_in[4];
  const float* b_hh = (const float*)d_in[5];
  const float* c1w  = (const float*)d_in[6];
  const float* bn1g = (const float*)d_in[7];  const float* bn1b=(const float*)d_in[8];
  const float* c2w  = (const float*)d_in[9];
  const float* bn2g = (const float*)d_in[10]; const float* bn2b=(const float*)d_in[11];
  const float* c3w  = (const float*)d_in[12];
  const float* bn3g = (const float*)d_in[13]; const float* bn3b=(const float*)d_in[14];
  const float* o1w  = (const float*)d_in[15];
  const float* bn4g = (const float*)d_in[16]; const float* bn4b=(const float*)d_in[17];
  const float* o2w  = (const float*)d_in[18]; const float* o2b =(const float*)d_in[19];

  char* ws = (char*)d_ws;
  // region0: raw conv out (bf16, max NPIX*128)
  unsigned short* Rb  = (unsigned short*)(ws + 0);          // 33554432 B
  // region1: A1b / A3b
  unsigned short* A1b = (unsigned short*)(ws + 33554432);   // 33554432 B
  unsigned short* A3b = A1b;
  // region2: Sb / A2b / A4b
  unsigned short* Sb  = (unsigned short*)(ws + 67108864);   // 33554432 B
  unsigned short* A2b = Sb;
  unsigned short* A4b = Sb;
  unsigned short* W1b = (unsigned short*)(ws + 100663296);  // 1605632 B
  unsigned short* W2b = (unsigned short*)(ws + 102268928);  // 147456 B
  unsigned short* W3b = (unsigned short*)(ws + 102416384);  // 55296 B
  unsigned short* W4b = (unsigned short*)(ws + 102471680);  // 55296 B
  unsigned short* WGb = (unsigned short*)(ws + 102526976);  // 147456 B
  float* partials = (float*)(ws + 102674432);               // 1048576 B
  float2* stats   = (float2*)(ws + 103723008);              // 1024 B
  int*   flags    = (int*)  (ws + 103724032);               // 32 B

  float* semmap = (float*)d_out;                 // [2][20][256][256]
  float* obsout = (float*)d_out + 2621440;       // [2][256][256] as float

  prep_gru_wb<<<288,256,0,stream>>>(w_ih,w_hh,WGb);
  prep_conv_w<<<(49*4*128*32+255)/256,256,0,stream>>>(c1w,W1b,128,4,128,7,49*4*128*32);
  prep_conv_w<<<(9*4*64*32 +255)/256,256,0,stream>>>(c2w,W2b,128,4,64,3,9*4*64*32);
  prep_conv_w<<<(9*2*48*32 +255)/256,256,0,stream>>>(c3w,W3b,64,2,48,3,9*2*48*32);
  prep_conv_w<<<(9*2*48*32 +255)/256,256,0,stream>>>(o1w,W4b,48,2,48,3,9*2*48*32);

  flags_kernel<<<8,256,0,stream>>>(masks,flags);
  obs_kernel<<<512,256,0,stream>>>(masks,flags,obsout);

  gru_mfma<<<2048,256,0,stream>>>(feat,masks,WGb,b_ih,b_hh,Sb);

  // conv1: 512 threads, waves 2(M) x 4(N)
  mconv<128,128,128,7,512,2,4><<<1024,512,0,stream>>>(Sb,W1b,Rb,partials);
  stats_kernel<<<128,256,0,stream>>>(partials,bn1g,bn1b,stats,128,1024);
  bnrelu_b2b<<<4096,256,0,stream>>>(Rb,A1b,stats,16,NPIX*128/8);

  // conv2: 512 threads, waves 4(M) x 2(N)
  mconv<128,128,64,3,512,4,2><<<1024,512,0,stream>>>(A1b,W2b,Rb,partials);
  stats_kernel<<<64,256,0,stream>>>(partials,bn2g,bn2b,stats,64,1024);
  bnrelu_b2b<<<4096,256,0,stream>>>(Rb,A2b,stats,8,NPIX*64/8);

  // conv3: 256 threads, waves 4(M) x 1(N)
  mconv<64,64,48,3,256,4,1><<<1024,256,0,stream>>>(A2b,W3b,Rb,partials);
  stats_kernel<<<48,256,0,stream>>>(partials,bn3g,bn3b,stats,48,1024);
  bnrelu_b2b<<<4096,256,0,stream>>>(Rb,A3b,stats,6,NPIX*48/8);

  // conv4
  mconv<48,64,48,3,256,4,1><<<1024,256,0,stream>>>(A3b,W4b,Rb,partials);
  stats_kernel<<<48,256,0,stream>>>(partials,bn4g,bn4b,stats,48,1024);
  bnrelu_b2b<<<4096,256,0,stream>>>(Rb,A4b,stats,6,NPIX*48/8);

  obj2_kernel<<<512,256,0,stream>>>(A4b,o2w,o2b,semmap);
}